// Round 17
// baseline (300.301 us; speedup 1.0000x reference)
//
#include <hip/hip_runtime.h>
#include <hip/hip_bf16.h>
#include <math.h>

#define HW 4096
#define SCALE 0.17677669529663687f
#define LOG2E 1.4426950408889634f

typedef __attribute__((ext_vector_type(8))) short short8;
typedef __attribute__((ext_vector_type(4))) float f32x4;
typedef __attribute__((ext_vector_type(4))) unsigned int u32x4;
typedef __attribute__((ext_vector_type(2))) unsigned int u32x2;
typedef __attribute__((ext_vector_type(2), aligned(8))) unsigned int u32x2a;

static __device__ __forceinline__ unsigned short bf16b(float f) {
  __hip_bfloat16 h = __float2bfloat16(f);
  return *reinterpret_cast<unsigned short*>(&h);
}

// ---- GEMM: Y[256][4096] = W @ X + b. 1 px/thread, o-tile 8, grid 512 (2 blocks/CU).
__global__ __launch_bounds__(256) void gemm256(const float* __restrict__ W,
                                               const float* __restrict__ bias,
                                               const float* __restrict__ X,
                                               float* __restrict__ Yf,
                                               unsigned short* __restrict__ Yt,
                                               float sc) {
  int tid = threadIdx.x;
  int o0 = (blockIdx.x >> 4) * 8;          // 32 o-groups
  int p = (blockIdx.x & 15) * 256 + tid;   // 16 p-tiles of 256
  const float* Wb = W + o0 * 256;
  float acc[8];
  #pragma unroll
  for (int i = 0; i < 8; ++i) acc[i] = 0.f;
  #pragma unroll 4
  for (int c = 0; c < 256; ++c) {
    float xv = X[c * HW + p];
    #pragma unroll
    for (int i = 0; i < 8; ++i) acc[i] += Wb[i * 256 + c] * xv;
  }
  float r[8];
  #pragma unroll
  for (int i = 0; i < 8; ++i) r[i] = acc[i] + bias[o0 + i];
  if (Yf) {
    #pragma unroll
    for (int i = 0; i < 8; ++i) Yf[(size_t)(o0 + i) * HW + p] = r[i];
  }
  if (Yt) {
    int h = o0 >> 5, c0 = o0 & 31;
    u32x4 pk;
    #pragma unroll
    for (int j = 0; j < 4; ++j)
      pk[j] = (unsigned int)bf16b(r[2 * j] * sc) | ((unsigned int)bf16b(r[2 * j + 1] * sc) << 16);
    *(u32x4*)(Yt + ((size_t)(h * HW + p) * 32 + c0)) = pk;
  }
}

// ---- fused K+V projection, 1 px/thread, grid 512 ----
__global__ __launch_bounds__(256) void gemm_kv(const float* __restrict__ Wk,
                                               const float* __restrict__ bk,
                                               const float* __restrict__ Wv,
                                               const float* __restrict__ bv,
                                               const float* __restrict__ X,
                                               unsigned short* __restrict__ Yt,
                                               unsigned short* __restrict__ Yv) {
  int tid = threadIdx.x;
  int o0 = (blockIdx.x >> 4) * 8;
  int p = (blockIdx.x & 15) * 256 + tid;
  const float* Wkb = Wk + o0 * 256;
  const float* Wvb = Wv + o0 * 256;
  float ka[8], va[8];
  #pragma unroll
  for (int i = 0; i < 8; ++i) { ka[i] = 0.f; va[i] = 0.f; }
  #pragma unroll 2
  for (int c = 0; c < 256; ++c) {
    float xv = X[c * HW + p];
    #pragma unroll
    for (int i = 0; i < 8; ++i) {
      ka[i] += Wkb[i * 256 + c] * xv;
      va[i] += Wvb[i * 256 + c] * xv;
    }
  }
  {
    int h = o0 >> 5, c0 = o0 & 31;
    u32x4 pk;
    #pragma unroll
    for (int j = 0; j < 4; ++j) {
      float k0 = ka[2 * j] + bk[o0 + 2 * j];
      float k1 = ka[2 * j + 1] + bk[o0 + 2 * j + 1];
      pk[j] = (unsigned int)bf16b(k0) | ((unsigned int)bf16b(k1) << 16);
    }
    *(u32x4*)(Yt + ((size_t)(h * HW + p) * 32 + c0)) = pk;
  }
  #pragma unroll
  for (int i = 0; i < 8; ++i)
    Yv[(size_t)(o0 + i) * HW + p] = bf16b(va[i] + bv[o0 + i]);
}

// ---- depthwise 9x9 conv: 8 y-outputs per thread, 16-row sliding window ----
__global__ __launch_bounds__(256) void dwconv_kernel(const float* __restrict__ q,
                                                     const float* __restrict__ wdw,
                                                     const float* __restrict__ bdw,
                                                     float* __restrict__ o) {
  int x = threadIdx.x & 63;
  int w = threadIdx.x >> 6;
  int bid = blockIdx.x;               // g*128 + c*2 + half
  int half = bid & 1; int c = (bid >> 1) & 63; int g = bid >> 7;
  int y0 = half * 32 + w * 8;
  const float* qc = q + (g * 64 + c) * HW;
  const float* wc = wdw + c * 81;
  float b = bdw[c];
  float acc[8];
  #pragma unroll
  for (int i = 0; i < 8; ++i) acc[i] = b;
  #pragma unroll
  for (int r = 0; r < 16; ++r) {
    int yy = y0 - 4 + r;
    bool rowok = (unsigned)yy <= 63u;
    int yc = min(max(yy, 0), 63);
    float v[9];
    #pragma unroll
    for (int kx = 0; kx < 9; ++kx) {
      int xx = x + kx - 4;
      bool ok = rowok && ((unsigned)xx <= 63u);
      int xc = min(max(xx, 0), 63);
      float lv = qc[yc * 64 + xc];
      v[kx] = ok ? lv : 0.f;
    }
    #pragma unroll
    for (int oy = 0; oy < 8; ++oy) {
      int ky = r - oy;
      if (ky < 0 || ky > 8) continue;
      #pragma unroll
      for (int kx = 0; kx < 9; ++kx)
        acc[oy] += wc[ky * 9 + kx] * v[kx];
    }
  }
  #pragma unroll
  for (int oy = 0; oy < 8; ++oy)
    o[(g * 64 + c) * HW + (y0 + oy) * 64 + x] = acc[oy];
}

// ---- LN + GELU + pointwise + tanh -> pos/cxy (shuffle version, grid 4096) ----
__global__ __launch_bounds__(256) void ln_offset_kernel(const float* __restrict__ o,
                                                        const float* __restrict__ ln_g,
                                                        const float* __restrict__ ln_b,
                                                        const float* __restrict__ wpw,
                                                        float* __restrict__ pos,
                                                        float* __restrict__ cxy) {
  int wave = threadIdx.x >> 6;
  int c = threadIdx.x & 63;
  int bid = blockIdx.x;
  int xc = bid & 15; int y = (bid >> 4) & 63; int g = bid >> 10;
  int x = xc * 4 + wave;
  int p = y * 64 + x;
  float v = o[(g * 64 + c) * HW + p];
  float s = v, s2 = v * v;
  #pragma unroll
  for (int m = 32; m; m >>= 1) { s += __shfl_xor(s, m); s2 += __shfl_xor(s2, m); }
  float mu = s * (1.f / 64.f);
  float var = s2 * (1.f / 64.f) - mu * mu;
  float nv = (v - mu) * rsqrtf(var + 1e-5f) * ln_g[c] + ln_b[c];
  nv = 0.5f * nv * (1.f + erff(nv * 0.70710678118654752f));
  float t0 = wpw[c] * nv, t1 = wpw[64 + c] * nv;
  #pragma unroll
  for (int m = 32; m; m >>= 1) { t0 += __shfl_xor(t0, m); t1 += __shfl_xor(t1, m); }
  if (c == 0) {
    float offy = tanhf(t0) * (2.0f / 64.0f);
    float offx = tanhf(t1) * (2.0f / 64.0f);
    float py = offy + (y + 0.5f) * (2.f / 64.f) - 1.f;
    float px = offx + (x + 0.5f) * (2.f / 64.f) - 1.f;
    pos[(g * HW + p) * 2 + 0] = py;
    pos[(g * HW + p) * 2 + 1] = px;
    cxy[(g * HW + p) * 2 + 0] = 64.0f - 31.5f * px;
    cxy[(g * HW + p) * 2 + 1] = 64.0f - 31.5f * py;
  }
}

// ---- bilinear sample of x at pos -> xs[256][4096]; 4 channels/thread, grid 1024 ----
__global__ __launch_bounds__(256) void sample_kernel(const float* __restrict__ x,
                                                     const float* __restrict__ pos,
                                                     float* __restrict__ xs) {
  int bid = blockIdx.x;  // g*256 + nt*16 + cc
  int cc = bid & 15; int nt = (bid >> 4) & 15; int g = bid >> 8;
  int n = nt * 256 + threadIdx.x;
  float py = pos[(g * HW + n) * 2 + 0];
  float px = pos[(g * HW + n) * 2 + 1];
  float gx = (px + 1.f) * 31.5f;
  float gy = (py + 1.f) * 31.5f;
  float xf = floorf(gx), yf = floorf(gy);
  int xi = (int)xf, yi = (int)yf;
  float fx = gx - xf, fy = gy - yf;
  int x0c = min(max(xi, 0), 63), x1c = min(max(xi + 1, 0), 63);
  int y0c = min(max(yi, 0), 63), y1c = min(max(yi + 1, 0), 63);
  float wx0 = ((unsigned)xi <= 63u) ? (1.f - fx) : 0.f;
  float wx1 = ((unsigned)(xi + 1) <= 63u) ? fx : 0.f;
  float wy0 = ((unsigned)yi <= 63u) ? (1.f - fy) : 0.f;
  float wy1 = ((unsigned)(yi + 1) <= 63u) ? fy : 0.f;
  #pragma unroll
  for (int ci = 0; ci < 4; ++ci) {
    int c = cc * 4 + ci;
    const float* xp = x + (g * 64 + c) * HW;
    float vsum = wy0 * (wx0 * xp[y0c * 64 + x0c] + wx1 * xp[y0c * 64 + x1c]) +
                 wy1 * (wx0 * xp[y1c * 64 + x0c] + wx1 * xp[y1c * 64 + x1c]);
    xs[(g * 64 + c) * HW + n] = vsum;
  }
}

// ---- build 4-corner bf16-packed, zero-padded, log2e-scaled RPE tables ----
__global__ __launch_bounds__(256) void build_rpe4_kernel(const float* __restrict__ rpe,
                                                         unsigned int* __restrict__ tab4) {
  int idx = blockIdx.x * 256 + threadIdx.x;
  if (idx >= 8 * 16641) return;
  int h = idx / 16641; int r = idx - h * 16641;
  int y = r / 129, x = r - y * 129;
  const float* tb = rpe + h * 16129;
  auto pad = [&](int yy, int xx) -> float {
    if (yy < 1 || yy > 127 || xx < 1 || xx > 127) return 0.f;
    return tb[(yy - 1) * 127 + (xx - 1)] * LOG2E;
  };
  unsigned int w0 = (unsigned int)bf16b(pad(y, x)) | ((unsigned int)bf16b(pad(y + 1, x)) << 16);
  unsigned int w1 = (unsigned int)bf16b(pad(y, x + 1)) | ((unsigned int)bf16b(pad(y + 1, x + 1)) << 16);
  u32x2 v = {w0, w1};
  *(u32x2*)(tab4 + (size_t)idx * 2) = v;
}

// ---- fused attention: dense window loads + ds_bpermute instead of scattered gathers ----
// Each 16-query tile lies within ONE image row, so per (gather, lane-group):
// key n uniform, gy uniform, and the 16 lanes' gx form a ramp of step 63/64.
// Window: lane lm loads tab4 entry (y0, xb+lm) where xb = floor(exb+cx) is uniform;
// lane's entry j = floor(gx)-xb in [0,15] fetched via 2x ds_bpermute.
__global__ __launch_bounds__(256, 3) void attn_kernel(const unsigned short* __restrict__ qt,
                                                      const unsigned short* __restrict__ kt,
                                                      const unsigned short* __restrict__ vbuf,
                                                      const float* __restrict__ cxy,
                                                      const unsigned int* __restrict__ tab4,
                                                      float* __restrict__ att) {
  __shared__ __align__(16) unsigned int P_pack[4][16][20];
  __shared__ float red_l[4][16];
  __shared__ float red_acc[4][32][16];

  int tid = threadIdx.x;
  int w = tid >> 6;
  int l = tid & 63;
  int lm = l & 15;   // column: query m
  int lg = l >> 4;   // lane group
  int h = blockIdx.x >> 8;
  int mt = blockIdx.x & 255;
  int m0 = mt * 16;
  int m = m0 + lm;
  int xm = m & 63, ym = m >> 6;
  float ex = (xm + 0.5f) * (63.0f / 64.0f) - 31.5f;
  float ey = (ym + 0.5f) * (63.0f / 64.0f) - 31.5f;
  float exb = ((m0 & 63) + 0.5f) * (63.0f / 64.0f) - 31.5f;  // first query's ex (uniform)
  const char* tabb = (const char*)tab4 + (size_t)h * 133128;  // 16641 * 8B per head
  const float* cbase = cxy + (size_t)(h >> 1) * HW * 2;

  short8 qf = *(const short8*)(qt + ((size_t)(h * HW + m) * 32 + 8 * lg));

  f32x4 oA = {0.f, 0.f, 0.f, 0.f};
  f32x4 oB = {0.f, 0.f, 0.f, 0.f};
  float l_lane = 0.f;

  // ---------------- prologue: fill the pipeline for it=0 ----------------
  float bias[8];
  float2 ccv[8];
  short8 ka, kb, va, vb;

  {
    float2 cc0[8];
    #pragma unroll
    for (int i = 0; i < 8; ++i) {
      int nl = 16 * (i >> 2) + 4 * lg + (i & 3);
      cc0[i] = *(const float2*)(cbase + (size_t)(w * 32 + nl) * 2);
    }
    int n0 = w * 32;
    ka = *(const short8*)(kt + ((size_t)(h * HW + n0 + lm) * 32 + 8 * lg));
    kb = *(const short8*)(kt + ((size_t)(h * HW + n0 + 16 + lm) * 32 + 8 * lg));
    va = *(const short8*)(vbuf + ((size_t)(h * 32 + lm) * HW + n0 + 8 * lg));
    vb = *(const short8*)(vbuf + ((size_t)(h * 32 + 16 + lm) * HW + n0 + 8 * lg));
    u32x2a wentry[8];
    float fxs[8], fys[8];
    int jidx[8];
    #pragma unroll
    for (int i = 0; i < 8; ++i) {
      float gxl = ex + cc0[i].x;
      float gyu = ey + cc0[i].y;
      float yfu = floorf(gyu);
      fys[i] = gyu - yfu;
      float xbf = floorf(exb + cc0[i].x);
      float xfl = floorf(gxl);
      fxs[i] = gxl - xfl;
      jidx[i] = (int)(xfl - xbf);
      unsigned woff = (unsigned)((((int)yfu * 129 + (int)xbf + lm) << 3));
      wentry[i] = *(const u32x2a*)(tabb + woff);
    }
    #pragma unroll
    for (int i = 0; i < 8; ++i) {
      int nl = 16 * (i >> 2) + 4 * lg + (i & 3);
      ccv[i] = *(const float2*)(cbase + (size_t)(128 + w * 32 + nl) * 2);
    }
    #pragma unroll
    for (int i = 0; i < 8; ++i) {
      int srcb = ((lg << 4) + jidx[i]) << 2;
      unsigned e0 = (unsigned)__builtin_amdgcn_ds_bpermute(srcb, (int)wentry[i][0]);
      unsigned e1 = (unsigned)__builtin_amdgcn_ds_bpermute(srcb, (int)wentry[i][1]);
      float a00 = __uint_as_float(e0 << 16);
      float a10 = __uint_as_float(e0 & 0xffff0000u);
      float a01 = __uint_as_float(e1 << 16);
      float a11 = __uint_as_float(e1 & 0xffff0000u);
      float ly0 = a00 + fys[i] * (a10 - a00);
      float ly1 = a01 + fys[i] * (a11 - a01);
      bias[i] = ly0 + fxs[i] * (ly1 - ly0);
    }
  }

  // ---------------- main loop ----------------
  #pragma unroll 2
  for (int it = 0; it < 32; ++it) {
    f32x4 z = {0.f, 0.f, 0.f, 0.f};
    f32x4 s0 = __builtin_amdgcn_mfma_f32_16x16x32_bf16(ka, qf, z, 0, 0, 0);
    f32x4 s1 = __builtin_amdgcn_mfma_f32_16x16x32_bf16(kb, qf, z, 0, 0, 0);

    // prefetch K/V for it+1
    int n0n = ((it + 1) & 31) * 128 + w * 32;
    short8 kan = *(const short8*)(kt + ((size_t)(h * HW + n0n + lm) * 32 + 8 * lg));
    short8 kbn = *(const short8*)(kt + ((size_t)(h * HW + n0n + 16 + lm) * 32 + 8 * lg));
    short8 van = *(const short8*)(vbuf + ((size_t)(h * 32 + lm) * HW + n0n + 8 * lg));
    short8 vbn = *(const short8*)(vbuf + ((size_t)(h * 32 + 16 + lm) * HW + n0n + 8 * lg));

    // issue dense window loads for it+1 (128B contiguous per lane-group)
    u32x2a wentry[8];
    float fxs[8], fys[8];
    int jidx[8];
    #pragma unroll
    for (int i = 0; i < 8; ++i) {
      float gxl = ex + ccv[i].x;
      float gyu = ey + ccv[i].y;
      float yfu = floorf(gyu);
      fys[i] = gyu - yfu;
      float xbf = floorf(exb + ccv[i].x);
      float xfl = floorf(gxl);
      fxs[i] = gxl - xfl;
      jidx[i] = (int)(xfl - xbf);
      unsigned woff = (unsigned)((((int)yfu * 129 + (int)xbf + lm) << 3));
      wentry[i] = *(const u32x2a*)(tabb + woff);
    }
    // load cxy for it+2
    int n0n2 = ((it + 2) & 31) * 128 + w * 32;
    float2 ccn[8];
    #pragma unroll
    for (int i = 0; i < 8; ++i) {
      int nl = 16 * (i >> 2) + 4 * lg + (i & 3);
      ccn[i] = *(const float2*)(cbase + (size_t)(n0n2 + nl) * 2);
    }

    // softmax for it (fixed scale; scale cancels in final divide)
    float p[8];
    #pragma unroll
    for (int i = 0; i < 8; ++i) {
      float qk = (i < 4) ? s0[i & 3] : s1[i & 3];
      p[i] = __builtin_amdgcn_exp2f(qk + bias[i]);
    }
    l_lane += ((p[0] + p[1]) + (p[2] + p[3])) + ((p[4] + p[5]) + (p[6] + p[7]));
    unsigned int w0 = (unsigned int)bf16b(p[0]) | ((unsigned int)bf16b(p[1]) << 16);
    unsigned int w1 = (unsigned int)bf16b(p[2]) | ((unsigned int)bf16b(p[3]) << 16);
    unsigned int w2 = (unsigned int)bf16b(p[4]) | ((unsigned int)bf16b(p[5]) << 16);
    unsigned int w3 = (unsigned int)bf16b(p[6]) | ((unsigned int)bf16b(p[7]) << 16);
    u32x2 wa = {w0, w1}, wb = {w2, w3};
    *(u32x2*)&P_pack[w][lm][2 * lg] = wa;
    *(u32x2*)&P_pack[w][lm][8 + 2 * lg] = wb;
    u32x4 pw = *(u32x4*)&P_pack[w][lm][4 * lg];
    union { u32x4 u; short8 s; } cv; cv.u = pw;
    oA = __builtin_amdgcn_mfma_f32_16x16x32_bf16(va, cv.s, oA, 0, 0, 0);
    oB = __builtin_amdgcn_mfma_f32_16x16x32_bf16(vb, cv.s, oB, 0, 0, 0);

    // finish bias for it+1: route window entries via bpermute, unpack, lerp
    #pragma unroll
    for (int i = 0; i < 8; ++i) {
      int srcb = ((lg << 4) + jidx[i]) << 2;
      unsigned e0 = (unsigned)__builtin_amdgcn_ds_bpermute(srcb, (int)wentry[i][0]);
      unsigned e1 = (unsigned)__builtin_amdgcn_ds_bpermute(srcb, (int)wentry[i][1]);
      float a00 = __uint_as_float(e0 << 16);
      float a10 = __uint_as_float(e0 & 0xffff0000u);
      float a01 = __uint_as_float(e1 << 16);
      float a11 = __uint_as_float(e1 & 0xffff0000u);
      float ly0 = a00 + fys[i] * (a10 - a00);
      float ly1 = a01 + fys[i] * (a11 - a01);
      bias[i] = ly0 + fxs[i] * (ly1 - ly0);
    }
    ka = kan; kb = kbn; va = van; vb = vbn;
    #pragma unroll
    for (int i = 0; i < 8; ++i) ccv[i] = ccn[i];
  }

  // ---------------- epilogue: cross-wave merge ----------------
  l_lane += __shfl_xor(l_lane, 16);
  l_lane += __shfl_xor(l_lane, 32);
  if (lg == 0) red_l[w][lm] = l_lane;
  #pragma unroll
  for (int r = 0; r < 4; ++r) {
    red_acc[w][4 * lg + r][lm] = oA[r];
    red_acc[w][16 + 4 * lg + r][lm] = oB[r];
  }
  __syncthreads();
  #pragma unroll
  for (int rep = 0; rep < 2; ++rep) {
    int idx = tid + rep * 256;
    int cl = idx >> 4, mm = idx & 15;
    float lsum = 0.f, osum = 0.f;
    #pragma unroll
    for (int ww = 0; ww < 4; ++ww) {
      lsum += red_l[ww][mm];
      osum += red_acc[ww][cl][mm];
    }
    att[(size_t)(h * 32 + cl) * HW + m0 + mm] = osum / lsum;
  }
}

extern "C" void kernel_launch(void* const* d_in, const int* in_sizes, int n_in,
                              void* d_out, int out_size, void* d_ws, size_t ws_size,
                              hipStream_t stream) {
  const float* x    = (const float*)d_in[0];
  const float* wq   = (const float*)d_in[1];
  const float* bq   = (const float*)d_in[2];
  const float* wk   = (const float*)d_in[3];
  const float* bk   = (const float*)d_in[4];
  const float* wv   = (const float*)d_in[5];
  const float* bv   = (const float*)d_in[6];
  const float* wdw  = (const float*)d_in[7];
  const float* bdw  = (const float*)d_in[8];
  const float* lng  = (const float*)d_in[9];
  const float* lnb  = (const float*)d_in[10];
  const float* wpw  = (const float*)d_in[11];
  const float* rpe  = (const float*)d_in[12];
  const float* wout = (const float*)d_in[13];
  const float* bout = (const float*)d_in[14];
  float* out = (float*)d_out;

  float* ws = (float*)d_ws;
  float* q_f32 = ws;                                        // 4MB (reused as xs)
  float* o_f32 = ws + (1 << 20);                            // 4MB (reused as att)
  unsigned short* qt  = (unsigned short*)(ws + (2 << 20));  // 2MB
  unsigned short* ktp = (unsigned short*)(ws + ((2 << 20) + (1 << 19)));  // 2MB
  unsigned short* vbp = (unsigned short*)(ws + (3 << 20));  // 2MB
  float* pos  = ws + ((3 << 20) + (1 << 19));               // 128KB
  float* cxy  = pos + 32768;                                // 128KB
  unsigned int* tab4 = (unsigned int*)(cxy + 32768);        // 1.06MB

  gemm256<<<512, 256, 0, stream>>>(wq, bq, x, q_f32, qt, SCALE * LOG2E);
  build_rpe4_kernel<<<521, 256, 0, stream>>>(rpe, tab4);
  dwconv_kernel<<<512, 256, 0, stream>>>(q_f32, wdw, bdw, o_f32);
  ln_offset_kernel<<<4096, 256, 0, stream>>>(o_f32, lng, lnb, wpw, pos, cxy);
  sample_kernel<<<1024, 256, 0, stream>>>(x, pos, q_f32);   // q_f32 := xs
  gemm_kv<<<512, 256, 0, stream>>>(wk, bk, wv, bv, q_f32, ktp, vbp);
  attn_kernel<<<2048, 256, 0, stream>>>(qt, ktp, vbp, cxy, tab4, o_f32);  // o_f32 := att
  gemm256<<<512, 256, 0, stream>>>(wout, bout, o_f32, out, nullptr, 1.0f);
}

// Round 18
// 293.684 us; speedup vs baseline: 1.0225x; 1.0225x over previous
//
#include <hip/hip_runtime.h>
#include <hip/hip_bf16.h>
#include <math.h>

#define HW 4096
#define SCALE 0.17677669529663687f
#define LOG2E 1.4426950408889634f

typedef __attribute__((ext_vector_type(8))) short short8;
typedef __attribute__((ext_vector_type(4))) float f32x4;
typedef __attribute__((ext_vector_type(4))) unsigned int u32x4;
typedef __attribute__((ext_vector_type(2))) unsigned int u32x2;
typedef __attribute__((ext_vector_type(2), aligned(8))) unsigned int u32x2a;

static __device__ __forceinline__ unsigned short bf16b(float f) {
  __hip_bfloat16 h = __float2bfloat16(f);
  return *reinterpret_cast<unsigned short*>(&h);
}

// ---- GEMM: Y[256][4096] = W @ X + b. 1 px/thread, o-tile 8, grid 512 (2 blocks/CU).
__global__ __launch_bounds__(256) void gemm256(const float* __restrict__ W,
                                               const float* __restrict__ bias,
                                               const float* __restrict__ X,
                                               float* __restrict__ Yf,
                                               unsigned short* __restrict__ Yt,
                                               float sc) {
  int tid = threadIdx.x;
  int o0 = (blockIdx.x >> 4) * 8;          // 32 o-groups
  int p = (blockIdx.x & 15) * 256 + tid;   // 16 p-tiles of 256
  const float* Wb = W + o0 * 256;
  float acc[8];
  #pragma unroll
  for (int i = 0; i < 8; ++i) acc[i] = 0.f;
  #pragma unroll 4
  for (int c = 0; c < 256; ++c) {
    float xv = X[c * HW + p];
    #pragma unroll
    for (int i = 0; i < 8; ++i) acc[i] += Wb[i * 256 + c] * xv;
  }
  float r[8];
  #pragma unroll
  for (int i = 0; i < 8; ++i) r[i] = acc[i] + bias[o0 + i];
  if (Yf) {
    #pragma unroll
    for (int i = 0; i < 8; ++i) Yf[(size_t)(o0 + i) * HW + p] = r[i];
  }
  if (Yt) {
    int h = o0 >> 5, c0 = o0 & 31;
    u32x4 pk;
    #pragma unroll
    for (int j = 0; j < 4; ++j)
      pk[j] = (unsigned int)bf16b(r[2 * j] * sc) | ((unsigned int)bf16b(r[2 * j + 1] * sc) << 16);
    *(u32x4*)(Yt + ((size_t)(h * HW + p) * 32 + c0)) = pk;
  }
}

// ---- fused K+V projection, 1 px/thread, grid 512 ----
__global__ __launch_bounds__(256) void gemm_kv(const float* __restrict__ Wk,
                                               const float* __restrict__ bk,
                                               const float* __restrict__ Wv,
                                               const float* __restrict__ bv,
                                               const float* __restrict__ X,
                                               unsigned short* __restrict__ Yt,
                                               unsigned short* __restrict__ Yv) {
  int tid = threadIdx.x;
  int o0 = (blockIdx.x >> 4) * 8;
  int p = (blockIdx.x & 15) * 256 + tid;
  const float* Wkb = Wk + o0 * 256;
  const float* Wvb = Wv + o0 * 256;
  float ka[8], va[8];
  #pragma unroll
  for (int i = 0; i < 8; ++i) { ka[i] = 0.f; va[i] = 0.f; }
  #pragma unroll 2
  for (int c = 0; c < 256; ++c) {
    float xv = X[c * HW + p];
    #pragma unroll
    for (int i = 0; i < 8; ++i) {
      ka[i] += Wkb[i * 256 + c] * xv;
      va[i] += Wvb[i * 256 + c] * xv;
    }
  }
  {
    int h = o0 >> 5, c0 = o0 & 31;
    u32x4 pk;
    #pragma unroll
    for (int j = 0; j < 4; ++j) {
      float k0 = ka[2 * j] + bk[o0 + 2 * j];
      float k1 = ka[2 * j + 1] + bk[o0 + 2 * j + 1];
      pk[j] = (unsigned int)bf16b(k0) | ((unsigned int)bf16b(k1) << 16);
    }
    *(u32x4*)(Yt + ((size_t)(h * HW + p) * 32 + c0)) = pk;
  }
  #pragma unroll
  for (int i = 0; i < 8; ++i)
    Yv[(size_t)(o0 + i) * HW + p] = bf16b(va[i] + bv[o0 + i]);
}

// ---- depthwise 9x9 conv: 8 y-outputs per thread, 16-row sliding window ----
__global__ __launch_bounds__(256) void dwconv_kernel(const float* __restrict__ q,
                                                     const float* __restrict__ wdw,
                                                     const float* __restrict__ bdw,
                                                     float* __restrict__ o) {
  int x = threadIdx.x & 63;
  int w = threadIdx.x >> 6;
  int bid = blockIdx.x;               // g*128 + c*2 + half
  int half = bid & 1; int c = (bid >> 1) & 63; int g = bid >> 7;
  int y0 = half * 32 + w * 8;
  const float* qc = q + (g * 64 + c) * HW;
  const float* wc = wdw + c * 81;
  float b = bdw[c];
  float acc[8];
  #pragma unroll
  for (int i = 0; i < 8; ++i) acc[i] = b;
  #pragma unroll
  for (int r = 0; r < 16; ++r) {
    int yy = y0 - 4 + r;
    bool rowok = (unsigned)yy <= 63u;
    int yc = min(max(yy, 0), 63);
    float v[9];
    #pragma unroll
    for (int kx = 0; kx < 9; ++kx) {
      int xx = x + kx - 4;
      bool ok = rowok && ((unsigned)xx <= 63u);
      int xc = min(max(xx, 0), 63);
      float lv = qc[yc * 64 + xc];
      v[kx] = ok ? lv : 0.f;
    }
    #pragma unroll
    for (int oy = 0; oy < 8; ++oy) {
      int ky = r - oy;
      if (ky < 0 || ky > 8) continue;
      #pragma unroll
      for (int kx = 0; kx < 9; ++kx)
        acc[oy] += wc[ky * 9 + kx] * v[kx];
    }
  }
  #pragma unroll
  for (int oy = 0; oy < 8; ++oy)
    o[(g * 64 + c) * HW + (y0 + oy) * 64 + x] = acc[oy];
}

// ---- LN + GELU + pointwise + tanh -> pos/cxy (shuffle version, grid 4096) ----
__global__ __launch_bounds__(256) void ln_offset_kernel(const float* __restrict__ o,
                                                        const float* __restrict__ ln_g,
                                                        const float* __restrict__ ln_b,
                                                        const float* __restrict__ wpw,
                                                        float* __restrict__ pos,
                                                        float* __restrict__ cxy) {
  int wave = threadIdx.x >> 6;
  int c = threadIdx.x & 63;
  int bid = blockIdx.x;
  int xc = bid & 15; int y = (bid >> 4) & 63; int g = bid >> 10;
  int x = xc * 4 + wave;
  int p = y * 64 + x;
  float v = o[(g * 64 + c) * HW + p];
  float s = v, s2 = v * v;
  #pragma unroll
  for (int m = 32; m; m >>= 1) { s += __shfl_xor(s, m); s2 += __shfl_xor(s2, m); }
  float mu = s * (1.f / 64.f);
  float var = s2 * (1.f / 64.f) - mu * mu;
  float nv = (v - mu) * rsqrtf(var + 1e-5f) * ln_g[c] + ln_b[c];
  nv = 0.5f * nv * (1.f + erff(nv * 0.70710678118654752f));
  float t0 = wpw[c] * nv, t1 = wpw[64 + c] * nv;
  #pragma unroll
  for (int m = 32; m; m >>= 1) { t0 += __shfl_xor(t0, m); t1 += __shfl_xor(t1, m); }
  if (c == 0) {
    float offy = tanhf(t0) * (2.0f / 64.0f);
    float offx = tanhf(t1) * (2.0f / 64.0f);
    float py = offy + (y + 0.5f) * (2.f / 64.f) - 1.f;
    float px = offx + (x + 0.5f) * (2.f / 64.f) - 1.f;
    pos[(g * HW + p) * 2 + 0] = py;
    pos[(g * HW + p) * 2 + 1] = px;
    cxy[(g * HW + p) * 2 + 0] = 64.0f - 31.5f * px;
    cxy[(g * HW + p) * 2 + 1] = 64.0f - 31.5f * py;
  }
}

// ---- bilinear sample of x at pos -> xs[256][4096]; 4 channels/thread, grid 1024 ----
__global__ __launch_bounds__(256) void sample_kernel(const float* __restrict__ x,
                                                     const float* __restrict__ pos,
                                                     float* __restrict__ xs) {
  int bid = blockIdx.x;  // g*256 + nt*16 + cc
  int cc = bid & 15; int nt = (bid >> 4) & 15; int g = bid >> 8;
  int n = nt * 256 + threadIdx.x;
  float py = pos[(g * HW + n) * 2 + 0];
  float px = pos[(g * HW + n) * 2 + 1];
  float gx = (px + 1.f) * 31.5f;
  float gy = (py + 1.f) * 31.5f;
  float xf = floorf(gx), yf = floorf(gy);
  int xi = (int)xf, yi = (int)yf;
  float fx = gx - xf, fy = gy - yf;
  int x0c = min(max(xi, 0), 63), x1c = min(max(xi + 1, 0), 63);
  int y0c = min(max(yi, 0), 63), y1c = min(max(yi + 1, 0), 63);
  float wx0 = ((unsigned)xi <= 63u) ? (1.f - fx) : 0.f;
  float wx1 = ((unsigned)(xi + 1) <= 63u) ? fx : 0.f;
  float wy0 = ((unsigned)yi <= 63u) ? (1.f - fy) : 0.f;
  float wy1 = ((unsigned)(yi + 1) <= 63u) ? fy : 0.f;
  #pragma unroll
  for (int ci = 0; ci < 4; ++ci) {
    int c = cc * 4 + ci;
    const float* xp = x + (g * 64 + c) * HW;
    float vsum = wy0 * (wx0 * xp[y0c * 64 + x0c] + wx1 * xp[y0c * 64 + x1c]) +
                 wy1 * (wx0 * xp[y1c * 64 + x0c] + wx1 * xp[y1c * 64 + x1c]);
    xs[(g * 64 + c) * HW + n] = vsum;
  }
}

// ---- build 4-corner bf16-packed, zero-padded, log2e-scaled RPE tables ----
__global__ __launch_bounds__(256) void build_rpe4_kernel(const float* __restrict__ rpe,
                                                         unsigned int* __restrict__ tab4) {
  int idx = blockIdx.x * 256 + threadIdx.x;
  if (idx >= 8 * 16641) return;
  int h = idx / 16641; int r = idx - h * 16641;
  int y = r / 129, x = r - y * 129;
  const float* tb = rpe + h * 16129;
  auto pad = [&](int yy, int xx) -> float {
    if (yy < 1 || yy > 127 || xx < 1 || xx > 127) return 0.f;
    return tb[(yy - 1) * 127 + (xx - 1)] * LOG2E;
  };
  unsigned int w0 = (unsigned int)bf16b(pad(y, x)) | ((unsigned int)bf16b(pad(y + 1, x)) << 16);
  unsigned int w1 = (unsigned int)bf16b(pad(y, x + 1)) | ((unsigned int)bf16b(pad(y + 1, x + 1)) << 16);
  u32x2 v = {w0, w1};
  *(u32x2*)(tab4 + (size_t)idx * 2) = v;
}

// ---- fused attention: BOTH heads of a group per block (shared bilinear address math) ----
// R12 pipeline structure; per-pair addr math computed once, two table gathers + lerps.
__global__ __launch_bounds__(256, 3) void attn_kernel(const unsigned short* __restrict__ qt,
                                                      const unsigned short* __restrict__ kt,
                                                      const unsigned short* __restrict__ vbuf,
                                                      const float* __restrict__ cxy,
                                                      const unsigned int* __restrict__ tab4,
                                                      float* __restrict__ att) {
  __shared__ __align__(16) unsigned int P_pack[2][4][16][20];
  __shared__ float red_l[2][4][16];
  __shared__ float red_acc[2][4][32][16];

  int tid = threadIdx.x;
  int w = tid >> 6;
  int l = tid & 63;
  int lm = l & 15;   // column: query m
  int lg = l >> 4;   // lane group
  int g = blockIdx.x >> 8;
  int mt = blockIdx.x & 255;
  int m0 = mt * 16;
  int m = m0 + lm;
  int xm = m & 63, ym = m >> 6;
  float ex = (xm + 0.5f) * (63.0f / 64.0f) - 31.5f;
  float ey = (ym + 0.5f) * (63.0f / 64.0f) - 31.5f;
  int h0 = g * 2;
  const char* tb0 = (const char*)tab4 + (size_t)h0 * 133128;
  const char* tb1 = tb0 + 133128;
  const float* cbase = cxy + (size_t)g * HW * 2;

  short8 qf0 = *(const short8*)(qt + ((size_t)(h0 * HW + m) * 32 + 8 * lg));
  short8 qf1 = *(const short8*)(qt + ((size_t)((h0 + 1) * HW + m) * 32 + 8 * lg));

  f32x4 o0A = {0.f, 0.f, 0.f, 0.f}, o0B = {0.f, 0.f, 0.f, 0.f};
  f32x4 o1A = {0.f, 0.f, 0.f, 0.f}, o1B = {0.f, 0.f, 0.f, 0.f};
  float l0 = 0.f, l1 = 0.f;

  // ---------------- prologue ----------------
  float bias0[8], bias1[8];
  float2 ccv[8];
  short8 k0a, k0b, v0a, v0b, k1a, k1b, v1a, v1b;

  {
    float2 cc0[8];
    #pragma unroll
    for (int i = 0; i < 8; ++i) {
      int nl = 16 * (i >> 2) + 4 * lg + (i & 3);
      cc0[i] = *(const float2*)(cbase + (size_t)(w * 32 + nl) * 2);
    }
    int n0 = w * 32;
    k0a = *(const short8*)(kt + ((size_t)(h0 * HW + n0 + lm) * 32 + 8 * lg));
    k0b = *(const short8*)(kt + ((size_t)(h0 * HW + n0 + 16 + lm) * 32 + 8 * lg));
    v0a = *(const short8*)(vbuf + ((size_t)(h0 * 32 + lm) * HW + n0 + 8 * lg));
    v0b = *(const short8*)(vbuf + ((size_t)(h0 * 32 + 16 + lm) * HW + n0 + 8 * lg));
    k1a = *(const short8*)(kt + ((size_t)((h0 + 1) * HW + n0 + lm) * 32 + 8 * lg));
    k1b = *(const short8*)(kt + ((size_t)((h0 + 1) * HW + n0 + 16 + lm) * 32 + 8 * lg));
    v1a = *(const short8*)(vbuf + ((size_t)((h0 + 1) * 32 + lm) * HW + n0 + 8 * lg));
    v1b = *(const short8*)(vbuf + ((size_t)((h0 + 1) * 32 + 16 + lm) * HW + n0 + 8 * lg));
    u32x2a t0[8], t1[8];
    float fxs[8], fys[8];
    #pragma unroll
    for (int i = 0; i < 8; ++i) {
      float gx = ex + cc0[i].x, gy = ey + cc0[i].y;
      float xf = floorf(gx), yf = floorf(gy);
      fxs[i] = gx - xf; fys[i] = gy - yf;
      unsigned off = (unsigned)((int)yf * 1032 + ((int)xf << 3));
      t0[i] = *(const u32x2a*)(tb0 + off);
      t1[i] = *(const u32x2a*)(tb1 + off);
    }
    #pragma unroll
    for (int i = 0; i < 8; ++i) {
      int nl = 16 * (i >> 2) + 4 * lg + (i & 3);
      ccv[i] = *(const float2*)(cbase + (size_t)(128 + w * 32 + nl) * 2);
    }
    #pragma unroll
    for (int i = 0; i < 8; ++i) {
      float a00 = __uint_as_float(t0[i][0] << 16);
      float a10 = __uint_as_float(t0[i][0] & 0xffff0000u);
      float a01 = __uint_as_float(t0[i][1] << 16);
      float a11 = __uint_as_float(t0[i][1] & 0xffff0000u);
      float ly0 = a00 + fys[i] * (a10 - a00);
      float ly1 = a01 + fys[i] * (a11 - a01);
      bias0[i] = ly0 + fxs[i] * (ly1 - ly0);
      float b00 = __uint_as_float(t1[i][0] << 16);
      float b10 = __uint_as_float(t1[i][0] & 0xffff0000u);
      float b01 = __uint_as_float(t1[i][1] << 16);
      float b11 = __uint_as_float(t1[i][1] & 0xffff0000u);
      float my0 = b00 + fys[i] * (b10 - b00);
      float my1 = b01 + fys[i] * (b11 - b01);
      bias1[i] = my0 + fxs[i] * (my1 - my0);
    }
  }

  // ---------------- main loop ----------------
  for (int it = 0; it < 32; ++it) {
    f32x4 z = {0.f, 0.f, 0.f, 0.f};
    f32x4 s0a = __builtin_amdgcn_mfma_f32_16x16x32_bf16(k0a, qf0, z, 0, 0, 0);
    f32x4 s0b = __builtin_amdgcn_mfma_f32_16x16x32_bf16(k0b, qf0, z, 0, 0, 0);
    f32x4 s1a = __builtin_amdgcn_mfma_f32_16x16x32_bf16(k1a, qf1, z, 0, 0, 0);
    f32x4 s1b = __builtin_amdgcn_mfma_f32_16x16x32_bf16(k1b, qf1, z, 0, 0, 0);

    // prefetch K/V for it+1 (both heads)
    int n0n = ((it + 1) & 31) * 128 + w * 32;
    short8 k0an = *(const short8*)(kt + ((size_t)(h0 * HW + n0n + lm) * 32 + 8 * lg));
    short8 k0bn = *(const short8*)(kt + ((size_t)(h0 * HW + n0n + 16 + lm) * 32 + 8 * lg));
    short8 v0an = *(const short8*)(vbuf + ((size_t)(h0 * 32 + lm) * HW + n0n + 8 * lg));
    short8 v0bn = *(const short8*)(vbuf + ((size_t)(h0 * 32 + 16 + lm) * HW + n0n + 8 * lg));
    short8 k1an = *(const short8*)(kt + ((size_t)((h0 + 1) * HW + n0n + lm) * 32 + 8 * lg));
    short8 k1bn = *(const short8*)(kt + ((size_t)((h0 + 1) * HW + n0n + 16 + lm) * 32 + 8 * lg));
    short8 v1an = *(const short8*)(vbuf + ((size_t)((h0 + 1) * 32 + lm) * HW + n0n + 8 * lg));
    short8 v1bn = *(const short8*)(vbuf + ((size_t)((h0 + 1) * 32 + 16 + lm) * HW + n0n + 8 * lg));

    // table gathers for it+1 (shared address, two tables)
    u32x2a t0[8], t1[8];
    float fxs[8], fys[8];
    #pragma unroll
    for (int i = 0; i < 8; ++i) {
      float gx = ex + ccv[i].x, gy = ey + ccv[i].y;
      float xf = floorf(gx), yf = floorf(gy);
      fxs[i] = gx - xf; fys[i] = gy - yf;
      unsigned off = (unsigned)((int)yf * 1032 + ((int)xf << 3));
      t0[i] = *(const u32x2a*)(tb0 + off);
      t1[i] = *(const u32x2a*)(tb1 + off);
    }
    // cxy for it+2
    int n0n2 = ((it + 2) & 31) * 128 + w * 32;
    float2 ccn[8];
    #pragma unroll
    for (int i = 0; i < 8; ++i) {
      int nl = 16 * (i >> 2) + 4 * lg + (i & 3);
      ccn[i] = *(const float2*)(cbase + (size_t)(n0n2 + nl) * 2);
    }

    // softmax for it (both heads)
    float p0[8], p1[8];
    #pragma unroll
    for (int i = 0; i < 8; ++i) {
      float q0 = (i < 4) ? s0a[i & 3] : s0b[i & 3];
      float q1 = (i < 4) ? s1a[i & 3] : s1b[i & 3];
      p0[i] = __builtin_amdgcn_exp2f(q0 + bias0[i]);
      p1[i] = __builtin_amdgcn_exp2f(q1 + bias1[i]);
    }
    l0 += ((p0[0] + p0[1]) + (p0[2] + p0[3])) + ((p0[4] + p0[5]) + (p0[6] + p0[7]));
    l1 += ((p1[0] + p1[1]) + (p1[2] + p1[3])) + ((p1[4] + p1[5]) + (p1[6] + p1[7]));
    {
      unsigned int w0 = (unsigned int)bf16b(p0[0]) | ((unsigned int)bf16b(p0[1]) << 16);
      unsigned int w1 = (unsigned int)bf16b(p0[2]) | ((unsigned int)bf16b(p0[3]) << 16);
      unsigned int w2 = (unsigned int)bf16b(p0[4]) | ((unsigned int)bf16b(p0[5]) << 16);
      unsigned int w3 = (unsigned int)bf16b(p0[6]) | ((unsigned int)bf16b(p0[7]) << 16);
      u32x2 wa = {w0, w1}, wb = {w2, w3};
      *(u32x2*)&P_pack[0][w][lm][2 * lg] = wa;
      *(u32x2*)&P_pack[0][w][lm][8 + 2 * lg] = wb;
    }
    {
      unsigned int w0 = (unsigned int)bf16b(p1[0]) | ((unsigned int)bf16b(p1[1]) << 16);
      unsigned int w1 = (unsigned int)bf16b(p1[2]) | ((unsigned int)bf16b(p1[3]) << 16);
      unsigned int w2 = (unsigned int)bf16b(p1[4]) | ((unsigned int)bf16b(p1[5]) << 16);
      unsigned int w3 = (unsigned int)bf16b(p1[6]) | ((unsigned int)bf16b(p1[7]) << 16);
      u32x2 wa = {w0, w1}, wb = {w2, w3};
      *(u32x2*)&P_pack[1][w][lm][2 * lg] = wa;
      *(u32x2*)&P_pack[1][w][lm][8 + 2 * lg] = wb;
    }
    {
      u32x4 pw0 = *(u32x4*)&P_pack[0][w][lm][4 * lg];
      union { u32x4 u; short8 s; } c0; c0.u = pw0;
      o0A = __builtin_amdgcn_mfma_f32_16x16x32_bf16(v0a, c0.s, o0A, 0, 0, 0);
      o0B = __builtin_amdgcn_mfma_f32_16x16x32_bf16(v0b, c0.s, o0B, 0, 0, 0);
      u32x4 pw1 = *(u32x4*)&P_pack[1][w][lm][4 * lg];
      union { u32x4 u; short8 s; } c1; c1.u = pw1;
      o1A = __builtin_amdgcn_mfma_f32_16x16x32_bf16(v1a, c1.s, o1A, 0, 0, 0);
      o1B = __builtin_amdgcn_mfma_f32_16x16x32_bf16(v1b, c1.s, o1B, 0, 0, 0);
    }

    // finish bias for it+1 (both heads)
    #pragma unroll
    for (int i = 0; i < 8; ++i) {
      float a00 = __uint_as_float(t0[i][0] << 16);
      float a10 = __uint_as_float(t0[i][0] & 0xffff0000u);
      float a01 = __uint_as_float(t0[i][1] << 16);
      float a11 = __uint_as_float(t0[i][1] & 0xffff0000u);
      float ly0 = a00 + fys[i] * (a10 - a00);
      float ly1 = a01 + fys[i] * (a11 - a01);
      bias0[i] = ly0 + fxs[i] * (ly1 - ly0);
      float b00 = __uint_as_float(t1[i][0] << 16);
      float b10 = __uint_as_float(t1[i][0] & 0xffff0000u);
      float b01 = __uint_as_float(t1[i][1] << 16);
      float b11 = __uint_as_float(t1[i][1] & 0xffff0000u);
      float my0 = b00 + fys[i] * (b10 - b00);
      float my1 = b01 + fys[i] * (b11 - b01);
      bias1[i] = my0 + fxs[i] * (my1 - my0);
    }
    k0a = k0an; k0b = k0bn; v0a = v0an; v0b = v0bn;
    k1a = k1an; k1b = k1bn; v1a = v1an; v1b = v1bn;
    #pragma unroll
    for (int i = 0; i < 8; ++i) ccv[i] = ccn[i];
  }

  // ---------------- epilogue: cross-wave merge (both heads) ----------------
  l0 += __shfl_xor(l0, 16); l0 += __shfl_xor(l0, 32);
  l1 += __shfl_xor(l1, 16); l1 += __shfl_xor(l1, 32);
  if (lg == 0) { red_l[0][w][lm] = l0; red_l[1][w][lm] = l1; }
  #pragma unroll
  for (int r = 0; r < 4; ++r) {
    red_acc[0][w][4 * lg + r][lm] = o0A[r];
    red_acc[0][w][16 + 4 * lg + r][lm] = o0B[r];
    red_acc[1][w][4 * lg + r][lm] = o1A[r];
    red_acc[1][w][16 + 4 * lg + r][lm] = o1B[r];
  }
  __syncthreads();
  #pragma unroll
  for (int rep = 0; rep < 8; ++rep) {
    int idx = tid + rep * 256;   // hh*1024 + cl*16 + mm
    int hh = idx >> 10, cl = (idx >> 4) & 31, mm = idx & 15;
    float lsum = 0.f, osum = 0.f;
    #pragma unroll
    for (int ww = 0; ww < 4; ++ww) {
      lsum += red_l[hh][ww][mm];
      osum += red_acc[hh][ww][cl][mm];
    }
    att[(size_t)((h0 + hh) * 32 + cl) * HW + m0 + mm] = osum / lsum;
  }
}

extern "C" void kernel_launch(void* const* d_in, const int* in_sizes, int n_in,
                              void* d_out, int out_size, void* d_ws, size_t ws_size,
                              hipStream_t stream) {
  const float* x    = (const float*)d_in[0];
  const float* wq   = (const float*)d_in[1];
  const float* bq   = (const float*)d_in[2];
  const float* wk   = (const float*)d_in[3];
  const float* bk   = (const float*)d_in[4];
  const float* wv   = (const float*)d_in[5];
  const float* bv   = (const float*)d_in[6];
  const float* wdw  = (const float*)d_in[7];
  const float* bdw  = (const float*)d_in[8];
  const float* lng  = (const float*)d_in[9];
  const float* lnb  = (const float*)d_in[10];
  const float* wpw  = (const float*)d_in[11];
  const float* rpe  = (const float*)d_in[12];
  const float* wout = (const float*)d_in[13];
  const float* bout = (const float*)d_in[14];
  float* out = (float*)d_out;

  float* ws = (float*)d_ws;
  float* q_f32 = ws;                                        // 4MB (reused as xs)
  float* o_f32 = ws + (1 << 20);                            // 4MB (reused as att)
  unsigned short* qt  = (unsigned short*)(ws + (2 << 20));  // 2MB
  unsigned short* ktp = (unsigned short*)(ws + ((2 << 20) + (1 << 19)));  // 2MB
  unsigned short* vbp = (unsigned short*)(ws + (3 << 20));  // 2MB
  float* pos  = ws + ((3 << 20) + (1 << 19));               // 128KB
  float* cxy  = pos + 32768;                                // 128KB
  unsigned int* tab4 = (unsigned int*)(cxy + 32768);        // 1.06MB

  gemm256<<<512, 256, 0, stream>>>(wq, bq, x, q_f32, qt, SCALE * LOG2E);
  build_rpe4_kernel<<<521, 256, 0, stream>>>(rpe, tab4);
  dwconv_kernel<<<512, 256, 0, stream>>>(q_f32, wdw, bdw, o_f32);
  ln_offset_kernel<<<4096, 256, 0, stream>>>(o_f32, lng, lnb, wpw, pos, cxy);
  sample_kernel<<<1024, 256, 0, stream>>>(x, pos, q_f32);   // q_f32 := xs
  gemm_kv<<<512, 256, 0, stream>>>(wk, bk, wv, bv, q_f32, ktp, vbp);
  attn_kernel<<<1024, 256, 0, stream>>>(qt, ktp, vbp, cxy, tab4, o_f32);  // o_f32 := att
  gemm256<<<512, 256, 0, stream>>>(wout, bout, o_f32, out, nullptr, 1.0f);
}

// Round 19
// 278.119 us; speedup vs baseline: 1.0798x; 1.0560x over previous
//
#include <hip/hip_runtime.h>
#include <hip/hip_bf16.h>
#include <math.h>

#define HW 4096
#define SCALE 0.17677669529663687f
#define LOG2E 1.4426950408889634f

typedef __attribute__((ext_vector_type(8))) short short8;
typedef __attribute__((ext_vector_type(4))) float f32x4;
typedef __attribute__((ext_vector_type(4))) unsigned int u32x4;
typedef __attribute__((ext_vector_type(2))) unsigned int u32x2;
typedef __attribute__((ext_vector_type(2), aligned(8))) unsigned int u32x2a;

static __device__ __forceinline__ unsigned short bf16b(float f) {
  __hip_bfloat16 h = __float2bfloat16(f);
  return *reinterpret_cast<unsigned short*>(&h);
}

// ---- GEMM: Y[256][4096] = W @ X + b. 1 px/thread, o-tile 8, grid 512 (2 blocks/CU).
__global__ __launch_bounds__(256) void gemm256(const float* __restrict__ W,
                                               const float* __restrict__ bias,
                                               const float* __restrict__ X,
                                               float* __restrict__ Yf,
                                               unsigned short* __restrict__ Yt,
                                               float sc) {
  int tid = threadIdx.x;
  int o0 = (blockIdx.x >> 4) * 8;          // 32 o-groups
  int p = (blockIdx.x & 15) * 256 + tid;   // 16 p-tiles of 256
  const float* Wb = W + o0 * 256;
  float acc[8];
  #pragma unroll
  for (int i = 0; i < 8; ++i) acc[i] = 0.f;
  #pragma unroll 8
  for (int c = 0; c < 256; ++c) {
    float xv = X[c * HW + p];
    #pragma unroll
    for (int i = 0; i < 8; ++i) acc[i] += Wb[i * 256 + c] * xv;
  }
  float r[8];
  #pragma unroll
  for (int i = 0; i < 8; ++i) r[i] = acc[i] + bias[o0 + i];
  if (Yf) {
    #pragma unroll
    for (int i = 0; i < 8; ++i) Yf[(size_t)(o0 + i) * HW + p] = r[i];
  }
  if (Yt) {
    int h = o0 >> 5, c0 = o0 & 31;
    u32x4 pk;
    #pragma unroll
    for (int j = 0; j < 4; ++j)
      pk[j] = (unsigned int)bf16b(r[2 * j] * sc) | ((unsigned int)bf16b(r[2 * j + 1] * sc) << 16);
    *(u32x4*)(Yt + ((size_t)(h * HW + p) * 32 + c0)) = pk;
  }
}

// ---- fused K+V projection, 1 px/thread, grid 512 ----
__global__ __launch_bounds__(256) void gemm_kv(const float* __restrict__ Wk,
                                               const float* __restrict__ bk,
                                               const float* __restrict__ Wv,
                                               const float* __restrict__ bv,
                                               const float* __restrict__ X,
                                               unsigned short* __restrict__ Yt,
                                               unsigned short* __restrict__ Yv) {
  int tid = threadIdx.x;
  int o0 = (blockIdx.x >> 4) * 8;
  int p = (blockIdx.x & 15) * 256 + tid;
  const float* Wkb = Wk + o0 * 256;
  const float* Wvb = Wv + o0 * 256;
  float ka[8], va[8];
  #pragma unroll
  for (int i = 0; i < 8; ++i) { ka[i] = 0.f; va[i] = 0.f; }
  #pragma unroll 4
  for (int c = 0; c < 256; ++c) {
    float xv = X[c * HW + p];
    #pragma unroll
    for (int i = 0; i < 8; ++i) {
      ka[i] += Wkb[i * 256 + c] * xv;
      va[i] += Wvb[i * 256 + c] * xv;
    }
  }
  {
    int h = o0 >> 5, c0 = o0 & 31;
    u32x4 pk;
    #pragma unroll
    for (int j = 0; j < 4; ++j) {
      float k0 = ka[2 * j] + bk[o0 + 2 * j];
      float k1 = ka[2 * j + 1] + bk[o0 + 2 * j + 1];
      pk[j] = (unsigned int)bf16b(k0) | ((unsigned int)bf16b(k1) << 16);
    }
    *(u32x4*)(Yt + ((size_t)(h * HW + p) * 32 + c0)) = pk;
  }
  #pragma unroll
  for (int i = 0; i < 8; ++i)
    Yv[(size_t)(o0 + i) * HW + p] = bf16b(va[i] + bv[o0 + i]);
}

// ---- depthwise 9x9 conv: 8 y-outputs per thread, 16-row sliding window ----
__global__ __launch_bounds__(256) void dwconv_kernel(const float* __restrict__ q,
                                                     const float* __restrict__ wdw,
                                                     const float* __restrict__ bdw,
                                                     float* __restrict__ o) {
  int x = threadIdx.x & 63;
  int w = threadIdx.x >> 6;
  int bid = blockIdx.x;               // g*128 + c*2 + half
  int half = bid & 1; int c = (bid >> 1) & 63; int g = bid >> 7;
  int y0 = half * 32 + w * 8;
  const float* qc = q + (g * 64 + c) * HW;
  const float* wc = wdw + c * 81;
  float b = bdw[c];
  float acc[8];
  #pragma unroll
  for (int i = 0; i < 8; ++i) acc[i] = b;
  #pragma unroll
  for (int r = 0; r < 16; ++r) {
    int yy = y0 - 4 + r;
    bool rowok = (unsigned)yy <= 63u;
    int yc = min(max(yy, 0), 63);
    float v[9];
    #pragma unroll
    for (int kx = 0; kx < 9; ++kx) {
      int xx = x + kx - 4;
      bool ok = rowok && ((unsigned)xx <= 63u);
      int xc = min(max(xx, 0), 63);
      float lv = qc[yc * 64 + xc];
      v[kx] = ok ? lv : 0.f;
    }
    #pragma unroll
    for (int oy = 0; oy < 8; ++oy) {
      int ky = r - oy;
      if (ky < 0 || ky > 8) continue;
      #pragma unroll
      for (int kx = 0; kx < 9; ++kx)
        acc[oy] += wc[ky * 9 + kx] * v[kx];
    }
  }
  #pragma unroll
  for (int oy = 0; oy < 8; ++oy)
    o[(g * 64 + c) * HW + (y0 + oy) * 64 + x] = acc[oy];
}

// ---- LN + GELU + pointwise + tanh -> pos/cxy (shuffle version, grid 4096) ----
__global__ __launch_bounds__(256) void ln_offset_kernel(const float* __restrict__ o,
                                                        const float* __restrict__ ln_g,
                                                        const float* __restrict__ ln_b,
                                                        const float* __restrict__ wpw,
                                                        float* __restrict__ pos,
                                                        float* __restrict__ cxy) {
  int wave = threadIdx.x >> 6;
  int c = threadIdx.x & 63;
  int bid = blockIdx.x;
  int xc = bid & 15; int y = (bid >> 4) & 63; int g = bid >> 10;
  int x = xc * 4 + wave;
  int p = y * 64 + x;
  float v = o[(g * 64 + c) * HW + p];
  float s = v, s2 = v * v;
  #pragma unroll
  for (int m = 32; m; m >>= 1) { s += __shfl_xor(s, m); s2 += __shfl_xor(s2, m); }
  float mu = s * (1.f / 64.f);
  float var = s2 * (1.f / 64.f) - mu * mu;
  float nv = (v - mu) * rsqrtf(var + 1e-5f) * ln_g[c] + ln_b[c];
  nv = 0.5f * nv * (1.f + erff(nv * 0.70710678118654752f));
  float t0 = wpw[c] * nv, t1 = wpw[64 + c] * nv;
  #pragma unroll
  for (int m = 32; m; m >>= 1) { t0 += __shfl_xor(t0, m); t1 += __shfl_xor(t1, m); }
  if (c == 0) {
    float offy = tanhf(t0) * (2.0f / 64.0f);
    float offx = tanhf(t1) * (2.0f / 64.0f);
    float py = offy + (y + 0.5f) * (2.f / 64.f) - 1.f;
    float px = offx + (x + 0.5f) * (2.f / 64.f) - 1.f;
    pos[(g * HW + p) * 2 + 0] = py;
    pos[(g * HW + p) * 2 + 1] = px;
    cxy[(g * HW + p) * 2 + 0] = 64.0f - 31.5f * px;
    cxy[(g * HW + p) * 2 + 1] = 64.0f - 31.5f * py;
  }
}

// ---- bilinear sample of x at pos -> xs[256][4096]; 4 channels/thread, grid 1024 ----
__global__ __launch_bounds__(256) void sample_kernel(const float* __restrict__ x,
                                                     const float* __restrict__ pos,
                                                     float* __restrict__ xs) {
  int bid = blockIdx.x;  // g*256 + nt*16 + cc
  int cc = bid & 15; int nt = (bid >> 4) & 15; int g = bid >> 8;
  int n = nt * 256 + threadIdx.x;
  float py = pos[(g * HW + n) * 2 + 0];
  float px = pos[(g * HW + n) * 2 + 1];
  float gx = (px + 1.f) * 31.5f;
  float gy = (py + 1.f) * 31.5f;
  float xf = floorf(gx), yf = floorf(gy);
  int xi = (int)xf, yi = (int)yf;
  float fx = gx - xf, fy = gy - yf;
  int x0c = min(max(xi, 0), 63), x1c = min(max(xi + 1, 0), 63);
  int y0c = min(max(yi, 0), 63), y1c = min(max(yi + 1, 0), 63);
  float wx0 = ((unsigned)xi <= 63u) ? (1.f - fx) : 0.f;
  float wx1 = ((unsigned)(xi + 1) <= 63u) ? fx : 0.f;
  float wy0 = ((unsigned)yi <= 63u) ? (1.f - fy) : 0.f;
  float wy1 = ((unsigned)(yi + 1) <= 63u) ? fy : 0.f;
  #pragma unroll
  for (int ci = 0; ci < 4; ++ci) {
    int c = cc * 4 + ci;
    const float* xp = x + (g * 64 + c) * HW;
    float vsum = wy0 * (wx0 * xp[y0c * 64 + x0c] + wx1 * xp[y0c * 64 + x1c]) +
                 wy1 * (wx0 * xp[y1c * 64 + x0c] + wx1 * xp[y1c * 64 + x1c]);
    xs[(g * 64 + c) * HW + n] = vsum;
  }
}

// ---- build 4-corner bf16-packed, zero-padded, log2e-scaled RPE tables ----
__global__ __launch_bounds__(256) void build_rpe4_kernel(const float* __restrict__ rpe,
                                                         unsigned int* __restrict__ tab4) {
  int idx = blockIdx.x * 256 + threadIdx.x;
  if (idx >= 8 * 16641) return;
  int h = idx / 16641; int r = idx - h * 16641;
  int y = r / 129, x = r - y * 129;
  const float* tb = rpe + h * 16129;
  auto pad = [&](int yy, int xx) -> float {
    if (yy < 1 || yy > 127 || xx < 1 || xx > 127) return 0.f;
    return tb[(yy - 1) * 127 + (xx - 1)] * LOG2E;
  };
  unsigned int w0 = (unsigned int)bf16b(pad(y, x)) | ((unsigned int)bf16b(pad(y + 1, x)) << 16);
  unsigned int w1 = (unsigned int)bf16b(pad(y, x + 1)) | ((unsigned int)bf16b(pad(y + 1, x + 1)) << 16);
  u32x2 v = {w0, w1};
  *(u32x2*)(tab4 + (size_t)idx * 2) = v;
}

// ---- fused attention: BOTH heads of a group per block (shared bilinear address math) ----
__global__ __launch_bounds__(256, 3) void attn_kernel(const unsigned short* __restrict__ qt,
                                                      const unsigned short* __restrict__ kt,
                                                      const unsigned short* __restrict__ vbuf,
                                                      const float* __restrict__ cxy,
                                                      const unsigned int* __restrict__ tab4,
                                                      float* __restrict__ att) {
  __shared__ __align__(16) unsigned int P_pack[2][4][16][20];
  __shared__ float red_l[2][4][16];
  __shared__ float red_acc[2][4][32][16];

  int tid = threadIdx.x;
  int w = tid >> 6;
  int l = tid & 63;
  int lm = l & 15;   // column: query m
  int lg = l >> 4;   // lane group
  int g = blockIdx.x >> 8;
  int mt = blockIdx.x & 255;
  int m0 = mt * 16;
  int m = m0 + lm;
  int xm = m & 63, ym = m >> 6;
  float ex = (xm + 0.5f) * (63.0f / 64.0f) - 31.5f;
  float ey = (ym + 0.5f) * (63.0f / 64.0f) - 31.5f;
  int h0 = g * 2;
  const char* tb0 = (const char*)tab4 + (size_t)h0 * 133128;
  const char* tb1 = tb0 + 133128;
  const float* cbase = cxy + (size_t)g * HW * 2;

  short8 qf0 = *(const short8*)(qt + ((size_t)(h0 * HW + m) * 32 + 8 * lg));
  short8 qf1 = *(const short8*)(qt + ((size_t)((h0 + 1) * HW + m) * 32 + 8 * lg));

  f32x4 o0A = {0.f, 0.f, 0.f, 0.f}, o0B = {0.f, 0.f, 0.f, 0.f};
  f32x4 o1A = {0.f, 0.f, 0.f, 0.f}, o1B = {0.f, 0.f, 0.f, 0.f};
  float l0 = 0.f, l1 = 0.f;

  // ---------------- prologue ----------------
  float bias0[8], bias1[8];
  float2 ccv[8];
  short8 k0a, k0b, v0a, v0b, k1a, k1b, v1a, v1b;

  {
    float2 cc0[8];
    #pragma unroll
    for (int i = 0; i < 8; ++i) {
      int nl = 16 * (i >> 2) + 4 * lg + (i & 3);
      cc0[i] = *(const float2*)(cbase + (size_t)(w * 32 + nl) * 2);
    }
    int n0 = w * 32;
    k0a = *(const short8*)(kt + ((size_t)(h0 * HW + n0 + lm) * 32 + 8 * lg));
    k0b = *(const short8*)(kt + ((size_t)(h0 * HW + n0 + 16 + lm) * 32 + 8 * lg));
    v0a = *(const short8*)(vbuf + ((size_t)(h0 * 32 + lm) * HW + n0 + 8 * lg));
    v0b = *(const short8*)(vbuf + ((size_t)(h0 * 32 + 16 + lm) * HW + n0 + 8 * lg));
    k1a = *(const short8*)(kt + ((size_t)((h0 + 1) * HW + n0 + lm) * 32 + 8 * lg));
    k1b = *(const short8*)(kt + ((size_t)((h0 + 1) * HW + n0 + 16 + lm) * 32 + 8 * lg));
    v1a = *(const short8*)(vbuf + ((size_t)((h0 + 1) * 32 + lm) * HW + n0 + 8 * lg));
    v1b = *(const short8*)(vbuf + ((size_t)((h0 + 1) * 32 + 16 + lm) * HW + n0 + 8 * lg));
    u32x2a t0[8], t1[8];
    float fxs[8], fys[8];
    #pragma unroll
    for (int i = 0; i < 8; ++i) {
      float gx = ex + cc0[i].x, gy = ey + cc0[i].y;
      float xf = floorf(gx), yf = floorf(gy);
      fxs[i] = gx - xf; fys[i] = gy - yf;
      unsigned off = (unsigned)((int)yf * 1032 + ((int)xf << 3));
      t0[i] = *(const u32x2a*)(tb0 + off);
      t1[i] = *(const u32x2a*)(tb1 + off);
    }
    #pragma unroll
    for (int i = 0; i < 8; ++i) {
      int nl = 16 * (i >> 2) + 4 * lg + (i & 3);
      ccv[i] = *(const float2*)(cbase + (size_t)(128 + w * 32 + nl) * 2);
    }
    #pragma unroll
    for (int i = 0; i < 8; ++i) {
      float a00 = __uint_as_float(t0[i][0] << 16);
      float a10 = __uint_as_float(t0[i][0] & 0xffff0000u);
      float a01 = __uint_as_float(t0[i][1] << 16);
      float a11 = __uint_as_float(t0[i][1] & 0xffff0000u);
      float ly0 = a00 + fys[i] * (a10 - a00);
      float ly1 = a01 + fys[i] * (a11 - a01);
      bias0[i] = ly0 + fxs[i] * (ly1 - ly0);
      float b00 = __uint_as_float(t1[i][0] << 16);
      float b10 = __uint_as_float(t1[i][0] & 0xffff0000u);
      float b01 = __uint_as_float(t1[i][1] << 16);
      float b11 = __uint_as_float(t1[i][1] & 0xffff0000u);
      float my0 = b00 + fys[i] * (b10 - b00);
      float my1 = b01 + fys[i] * (b11 - b01);
      bias1[i] = my0 + fxs[i] * (my1 - my0);
    }
  }

  // ---------------- main loop ----------------
  for (int it = 0; it < 32; ++it) {
    f32x4 z = {0.f, 0.f, 0.f, 0.f};
    f32x4 s0a = __builtin_amdgcn_mfma_f32_16x16x32_bf16(k0a, qf0, z, 0, 0, 0);
    f32x4 s0b = __builtin_amdgcn_mfma_f32_16x16x32_bf16(k0b, qf0, z, 0, 0, 0);
    f32x4 s1a = __builtin_amdgcn_mfma_f32_16x16x32_bf16(k1a, qf1, z, 0, 0, 0);
    f32x4 s1b = __builtin_amdgcn_mfma_f32_16x16x32_bf16(k1b, qf1, z, 0, 0, 0);

    // prefetch K/V for it+1 (both heads)
    int n0n = ((it + 1) & 31) * 128 + w * 32;
    short8 k0an = *(const short8*)(kt + ((size_t)(h0 * HW + n0n + lm) * 32 + 8 * lg));
    short8 k0bn = *(const short8*)(kt + ((size_t)(h0 * HW + n0n + 16 + lm) * 32 + 8 * lg));
    short8 v0an = *(const short8*)(vbuf + ((size_t)(h0 * 32 + lm) * HW + n0n + 8 * lg));
    short8 v0bn = *(const short8*)(vbuf + ((size_t)(h0 * 32 + 16 + lm) * HW + n0n + 8 * lg));
    short8 k1an = *(const short8*)(kt + ((size_t)((h0 + 1) * HW + n0n + lm) * 32 + 8 * lg));
    short8 k1bn = *(const short8*)(kt + ((size_t)((h0 + 1) * HW + n0n + 16 + lm) * 32 + 8 * lg));
    short8 v1an = *(const short8*)(vbuf + ((size_t)((h0 + 1) * 32 + lm) * HW + n0n + 8 * lg));
    short8 v1bn = *(const short8*)(vbuf + ((size_t)((h0 + 1) * 32 + 16 + lm) * HW + n0n + 8 * lg));

    // table gathers for it+1 (shared address, two tables)
    u32x2a t0[8], t1[8];
    float fxs[8], fys[8];
    #pragma unroll
    for (int i = 0; i < 8; ++i) {
      float gx = ex + ccv[i].x, gy = ey + ccv[i].y;
      float xf = floorf(gx), yf = floorf(gy);
      fxs[i] = gx - xf; fys[i] = gy - yf;
      unsigned off = (unsigned)((int)yf * 1032 + ((int)xf << 3));
      t0[i] = *(const u32x2a*)(tb0 + off);
      t1[i] = *(const u32x2a*)(tb1 + off);
    }
    // cxy for it+2
    int n0n2 = ((it + 2) & 31) * 128 + w * 32;
    float2 ccn[8];
    #pragma unroll
    for (int i = 0; i < 8; ++i) {
      int nl = 16 * (i >> 2) + 4 * lg + (i & 3);
      ccn[i] = *(const float2*)(cbase + (size_t)(n0n2 + nl) * 2);
    }

    // softmax for it (both heads)
    float p0[8], p1[8];
    #pragma unroll
    for (int i = 0; i < 8; ++i) {
      float q0 = (i < 4) ? s0a[i & 3] : s0b[i & 3];
      float q1 = (i < 4) ? s1a[i & 3] : s1b[i & 3];
      p0[i] = __builtin_amdgcn_exp2f(q0 + bias0[i]);
      p1[i] = __builtin_amdgcn_exp2f(q1 + bias1[i]);
    }
    l0 += ((p0[0] + p0[1]) + (p0[2] + p0[3])) + ((p0[4] + p0[5]) + (p0[6] + p0[7]));
    l1 += ((p1[0] + p1[1]) + (p1[2] + p1[3])) + ((p1[4] + p1[5]) + (p1[6] + p1[7]));
    {
      unsigned int w0 = (unsigned int)bf16b(p0[0]) | ((unsigned int)bf16b(p0[1]) << 16);
      unsigned int w1 = (unsigned int)bf16b(p0[2]) | ((unsigned int)bf16b(p0[3]) << 16);
      unsigned int w2 = (unsigned int)bf16b(p0[4]) | ((unsigned int)bf16b(p0[5]) << 16);
      unsigned int w3 = (unsigned int)bf16b(p0[6]) | ((unsigned int)bf16b(p0[7]) << 16);
      u32x2 wa = {w0, w1}, wb = {w2, w3};
      *(u32x2*)&P_pack[0][w][lm][2 * lg] = wa;
      *(u32x2*)&P_pack[0][w][lm][8 + 2 * lg] = wb;
    }
    {
      unsigned int w0 = (unsigned int)bf16b(p1[0]) | ((unsigned int)bf16b(p1[1]) << 16);
      unsigned int w1 = (unsigned int)bf16b(p1[2]) | ((unsigned int)bf16b(p1[3]) << 16);
      unsigned int w2 = (unsigned int)bf16b(p1[4]) | ((unsigned int)bf16b(p1[5]) << 16);
      unsigned int w3 = (unsigned int)bf16b(p1[6]) | ((unsigned int)bf16b(p1[7]) << 16);
      u32x2 wa = {w0, w1}, wb = {w2, w3};
      *(u32x2*)&P_pack[1][w][lm][2 * lg] = wa;
      *(u32x2*)&P_pack[1][w][lm][8 + 2 * lg] = wb;
    }
    {
      u32x4 pw0 = *(u32x4*)&P_pack[0][w][lm][4 * lg];
      union { u32x4 u; short8 s; } c0; c0.u = pw0;
      o0A = __builtin_amdgcn_mfma_f32_16x16x32_bf16(v0a, c0.s, o0A, 0, 0, 0);
      o0B = __builtin_amdgcn_mfma_f32_16x16x32_bf16(v0b, c0.s, o0B, 0, 0, 0);
      u32x4 pw1 = *(u32x4*)&P_pack[1][w][lm][4 * lg];
      union { u32x4 u; short8 s; } c1; c1.u = pw1;
      o1A = __builtin_amdgcn_mfma_f32_16x16x32_bf16(v1a, c1.s, o1A, 0, 0, 0);
      o1B = __builtin_amdgcn_mfma_f32_16x16x32_bf16(v1b, c1.s, o1B, 0, 0, 0);
    }

    // finish bias for it+1 (both heads)
    #pragma unroll
    for (int i = 0; i < 8; ++i) {
      float a00 = __uint_as_float(t0[i][0] << 16);
      float a10 = __uint_as_float(t0[i][0] & 0xffff0000u);
      float a01 = __uint_as_float(t0[i][1] << 16);
      float a11 = __uint_as_float(t0[i][1] & 0xffff0000u);
      float ly0 = a00 + fys[i] * (a10 - a00);
      float ly1 = a01 + fys[i] * (a11 - a01);
      bias0[i] = ly0 + fxs[i] * (ly1 - ly0);
      float b00 = __uint_as_float(t1[i][0] << 16);
      float b10 = __uint_as_float(t1[i][0] & 0xffff0000u);
      float b01 = __uint_as_float(t1[i][1] << 16);
      float b11 = __uint_as_float(t1[i][1] & 0xffff0000u);
      float my0 = b00 + fys[i] * (b10 - b00);
      float my1 = b01 + fys[i] * (b11 - b01);
      bias1[i] = my0 + fxs[i] * (my1 - my0);
    }
    k0a = k0an; k0b = k0bn; v0a = v0an; v0b = v0bn;
    k1a = k1an; k1b = k1bn; v1a = v1an; v1b = v1bn;
    #pragma unroll
    for (int i = 0; i < 8; ++i) ccv[i] = ccn[i];
  }

  // ---------------- epilogue: cross-wave merge (both heads) ----------------
  l0 += __shfl_xor(l0, 16); l0 += __shfl_xor(l0, 32);
  l1 += __shfl_xor(l1, 16); l1 += __shfl_xor(l1, 32);
  if (lg == 0) { red_l[0][w][lm] = l0; red_l[1][w][lm] = l1; }
  #pragma unroll
  for (int r = 0; r < 4; ++r) {
    red_acc[0][w][4 * lg + r][lm] = o0A[r];
    red_acc[0][w][16 + 4 * lg + r][lm] = o0B[r];
    red_acc[1][w][4 * lg + r][lm] = o1A[r];
    red_acc[1][w][16 + 4 * lg + r][lm] = o1B[r];
  }
  __syncthreads();
  #pragma unroll
  for (int rep = 0; rep < 8; ++rep) {
    int idx = tid + rep * 256;   // hh*1024 + cl*16 + mm
    int hh = idx >> 10, cl = (idx >> 4) & 31, mm = idx & 15;
    float lsum = 0.f, osum = 0.f;
    #pragma unroll
    for (int ww = 0; ww < 4; ++ww) {
      lsum += red_l[hh][ww][mm];
      osum += red_acc[hh][ww][cl][mm];
    }
    att[(size_t)((h0 + hh) * 32 + cl) * HW + m0 + mm] = osum / lsum;
  }
}

extern "C" void kernel_launch(void* const* d_in, const int* in_sizes, int n_in,
                              void* d_out, int out_size, void* d_ws, size_t ws_size,
                              hipStream_t stream) {
  const float* x    = (const float*)d_in[0];
  const float* wq   = (const float*)d_in[1];
  const float* bq   = (const float*)d_in[2];
  const float* wk   = (const float*)d_in[3];
  const float* bk   = (const float*)d_in[4];
  const float* wv   = (const float*)d_in[5];
  const float* bv   = (const float*)d_in[6];
  const float* wdw  = (const float*)d_in[7];
  const float* bdw  = (const float*)d_in[8];
  const float* lng  = (const float*)d_in[9];
  const float* lnb  = (const float*)d_in[10];
  const float* wpw  = (const float*)d_in[11];
  const float* rpe  = (const float*)d_in[12];
  const float* wout = (const float*)d_in[13];
  const float* bout = (const float*)d_in[14];
  float* out = (float*)d_out;

  float* ws = (float*)d_ws;
  float* q_f32 = ws;                                        // 4MB (reused as xs)
  float* o_f32 = ws + (1 << 20);                            // 4MB (reused as att)
  unsigned short* qt  = (unsigned short*)(ws + (2 << 20));  // 2MB
  unsigned short* ktp = (unsigned short*)(ws + ((2 << 20) + (1 << 19)));  // 2MB
  unsigned short* vbp = (unsigned short*)(ws + (3 << 20));  // 2MB
  float* pos  = ws + ((3 << 20) + (1 << 19));               // 128KB
  float* cxy  = pos + 32768;                                // 128KB
  unsigned int* tab4 = (unsigned int*)(cxy + 32768);        // 1.06MB

  gemm256<<<512, 256, 0, stream>>>(wq, bq, x, q_f32, qt, SCALE * LOG2E);
  build_rpe4_kernel<<<521, 256, 0, stream>>>(rpe, tab4);
  dwconv_kernel<<<512, 256, 0, stream>>>(q_f32, wdw, bdw, o_f32);
  ln_offset_kernel<<<4096, 256, 0, stream>>>(o_f32, lng, lnb, wpw, pos, cxy);
  sample_kernel<<<1024, 256, 0, stream>>>(x, pos, q_f32);   // q_f32 := xs
  gemm_kv<<<512, 256, 0, stream>>>(wk, bk, wv, bv, q_f32, ktp, vbp);
  attn_kernel<<<1024, 256, 0, stream>>>(qt, ktp, vbp, cxy, tab4, o_f32);  // o_f32 := att
  gemm256<<<512, 256, 0, stream>>>(wout, bout, o_f32, out, nullptr, 1.0f);
}

// Round 20
// 276.091 us; speedup vs baseline: 1.0877x; 1.0073x over previous
//
#include <hip/hip_runtime.h>
#include <hip/hip_bf16.h>
#include <math.h>

#define HW 4096
#define SCALE 0.17677669529663687f
#define LOG2E 1.4426950408889634f

typedef __attribute__((ext_vector_type(8))) short short8;
typedef __attribute__((ext_vector_type(4))) float f32x4;
typedef __attribute__((ext_vector_type(4))) unsigned int u32x4;
typedef __attribute__((ext_vector_type(2))) unsigned int u32x2;
typedef __attribute__((ext_vector_type(2), aligned(8))) unsigned int u32x2a;

static __device__ __forceinline__ unsigned short bf16b(float f) {
  __hip_bfloat16 h = __float2bfloat16(f);
  return *reinterpret_cast<unsigned short*>(&h);
}

// ---- GEMM: Y[256][4096] = W @ X + b. 1 px/thread, o-tile 8, grid 512 (2 blocks/CU).
__global__ __launch_bounds__(256) void gemm256(const float* __restrict__ W,
                                               const float* __restrict__ bias,
                                               const float* __restrict__ X,
                                               float* __restrict__ Yf,
                                               unsigned short* __restrict__ Yt,
                                               float sc) {
  int tid = threadIdx.x;
  int o0 = (blockIdx.x >> 4) * 8;          // 32 o-groups
  int p = (blockIdx.x & 15) * 256 + tid;   // 16 p-tiles of 256
  const float* Wb = W + o0 * 256;
  float acc[8];
  #pragma unroll
  for (int i = 0; i < 8; ++i) acc[i] = 0.f;
  #pragma unroll 8
  for (int c = 0; c < 256; ++c) {
    float xv = X[c * HW + p];
    #pragma unroll
    for (int i = 0; i < 8; ++i) acc[i] += Wb[i * 256 + c] * xv;
  }
  float r[8];
  #pragma unroll
  for (int i = 0; i < 8; ++i) r[i] = acc[i] + bias[o0 + i];
  if (Yf) {
    #pragma unroll
    for (int i = 0; i < 8; ++i) Yf[(size_t)(o0 + i) * HW + p] = r[i];
  }
  if (Yt) {
    int h = o0 >> 5, c0 = o0 & 31;
    u32x4 pk;
    #pragma unroll
    for (int j = 0; j < 4; ++j)
      pk[j] = (unsigned int)bf16b(r[2 * j] * sc) | ((unsigned int)bf16b(r[2 * j + 1] * sc) << 16);
    *(u32x4*)(Yt + ((size_t)(h * HW + p) * 32 + c0)) = pk;
  }
}

// ---- fused K+V projection, 1 px/thread, grid 512 ----
__global__ __launch_bounds__(256) void gemm_kv(const float* __restrict__ Wk,
                                               const float* __restrict__ bk,
                                               const float* __restrict__ Wv,
                                               const float* __restrict__ bv,
                                               const float* __restrict__ X,
                                               unsigned short* __restrict__ Yt,
                                               unsigned short* __restrict__ Yv) {
  int tid = threadIdx.x;
  int o0 = (blockIdx.x >> 4) * 8;
  int p = (blockIdx.x & 15) * 256 + tid;
  const float* Wkb = Wk + o0 * 256;
  const float* Wvb = Wv + o0 * 256;
  float ka[8], va[8];
  #pragma unroll
  for (int i = 0; i < 8; ++i) { ka[i] = 0.f; va[i] = 0.f; }
  #pragma unroll 4
  for (int c = 0; c < 256; ++c) {
    float xv = X[c * HW + p];
    #pragma unroll
    for (int i = 0; i < 8; ++i) {
      ka[i] += Wkb[i * 256 + c] * xv;
      va[i] += Wvb[i * 256 + c] * xv;
    }
  }
  {
    int h = o0 >> 5, c0 = o0 & 31;
    u32x4 pk;
    #pragma unroll
    for (int j = 0; j < 4; ++j) {
      float k0 = ka[2 * j] + bk[o0 + 2 * j];
      float k1 = ka[2 * j + 1] + bk[o0 + 2 * j + 1];
      pk[j] = (unsigned int)bf16b(k0) | ((unsigned int)bf16b(k1) << 16);
    }
    *(u32x4*)(Yt + ((size_t)(h * HW + p) * 32 + c0)) = pk;
  }
  #pragma unroll
  for (int i = 0; i < 8; ++i)
    Yv[(size_t)(o0 + i) * HW + p] = bf16b(va[i] + bv[o0 + i]);
}

// ---- depthwise 9x9 conv: 8 y-outputs per thread, 16-row sliding window ----
__global__ __launch_bounds__(256) void dwconv_kernel(const float* __restrict__ q,
                                                     const float* __restrict__ wdw,
                                                     const float* __restrict__ bdw,
                                                     float* __restrict__ o) {
  int x = threadIdx.x & 63;
  int w = threadIdx.x >> 6;
  int bid = blockIdx.x;               // g*128 + c*2 + half
  int half = bid & 1; int c = (bid >> 1) & 63; int g = bid >> 7;
  int y0 = half * 32 + w * 8;
  const float* qc = q + (g * 64 + c) * HW;
  const float* wc = wdw + c * 81;
  float b = bdw[c];
  float acc[8];
  #pragma unroll
  for (int i = 0; i < 8; ++i) acc[i] = b;
  #pragma unroll
  for (int r = 0; r < 16; ++r) {
    int yy = y0 - 4 + r;
    bool rowok = (unsigned)yy <= 63u;
    int yc = min(max(yy, 0), 63);
    float v[9];
    #pragma unroll
    for (int kx = 0; kx < 9; ++kx) {
      int xx = x + kx - 4;
      bool ok = rowok && ((unsigned)xx <= 63u);
      int xc = min(max(xx, 0), 63);
      float lv = qc[yc * 64 + xc];
      v[kx] = ok ? lv : 0.f;
    }
    #pragma unroll
    for (int oy = 0; oy < 8; ++oy) {
      int ky = r - oy;
      if (ky < 0 || ky > 8) continue;
      #pragma unroll
      for (int kx = 0; kx < 9; ++kx)
        acc[oy] += wc[ky * 9 + kx] * v[kx];
    }
  }
  #pragma unroll
  for (int oy = 0; oy < 8; ++oy)
    o[(g * 64 + c) * HW + (y0 + oy) * 64 + x] = acc[oy];
}

// ---- LN + GELU + pointwise + tanh -> pos/cxy (shuffle version, grid 4096) ----
__global__ __launch_bounds__(256) void ln_offset_kernel(const float* __restrict__ o,
                                                        const float* __restrict__ ln_g,
                                                        const float* __restrict__ ln_b,
                                                        const float* __restrict__ wpw,
                                                        float* __restrict__ pos,
                                                        float* __restrict__ cxy) {
  int wave = threadIdx.x >> 6;
  int c = threadIdx.x & 63;
  int bid = blockIdx.x;
  int xc = bid & 15; int y = (bid >> 4) & 63; int g = bid >> 10;
  int x = xc * 4 + wave;
  int p = y * 64 + x;
  float v = o[(g * 64 + c) * HW + p];
  float s = v, s2 = v * v;
  #pragma unroll
  for (int m = 32; m; m >>= 1) { s += __shfl_xor(s, m); s2 += __shfl_xor(s2, m); }
  float mu = s * (1.f / 64.f);
  float var = s2 * (1.f / 64.f) - mu * mu;
  float nv = (v - mu) * rsqrtf(var + 1e-5f) * ln_g[c] + ln_b[c];
  nv = 0.5f * nv * (1.f + erff(nv * 0.70710678118654752f));
  float t0 = wpw[c] * nv, t1 = wpw[64 + c] * nv;
  #pragma unroll
  for (int m = 32; m; m >>= 1) { t0 += __shfl_xor(t0, m); t1 += __shfl_xor(t1, m); }
  if (c == 0) {
    float offy = tanhf(t0) * (2.0f / 64.0f);
    float offx = tanhf(t1) * (2.0f / 64.0f);
    float py = offy + (y + 0.5f) * (2.f / 64.f) - 1.f;
    float px = offx + (x + 0.5f) * (2.f / 64.f) - 1.f;
    pos[(g * HW + p) * 2 + 0] = py;
    pos[(g * HW + p) * 2 + 1] = px;
    cxy[(g * HW + p) * 2 + 0] = 64.0f - 31.5f * px;
    cxy[(g * HW + p) * 2 + 1] = 64.0f - 31.5f * py;
  }
}

// ---- bilinear sample of x at pos -> xs[256][4096]; 4 channels/thread, grid 1024 ----
__global__ __launch_bounds__(256) void sample_kernel(const float* __restrict__ x,
                                                     const float* __restrict__ pos,
                                                     float* __restrict__ xs) {
  int bid = blockIdx.x;  // g*256 + nt*16 + cc
  int cc = bid & 15; int nt = (bid >> 4) & 15; int g = bid >> 8;
  int n = nt * 256 + threadIdx.x;
  float py = pos[(g * HW + n) * 2 + 0];
  float px = pos[(g * HW + n) * 2 + 1];
  float gx = (px + 1.f) * 31.5f;
  float gy = (py + 1.f) * 31.5f;
  float xf = floorf(gx), yf = floorf(gy);
  int xi = (int)xf, yi = (int)yf;
  float fx = gx - xf, fy = gy - yf;
  int x0c = min(max(xi, 0), 63), x1c = min(max(xi + 1, 0), 63);
  int y0c = min(max(yi, 0), 63), y1c = min(max(yi + 1, 0), 63);
  float wx0 = ((unsigned)xi <= 63u) ? (1.f - fx) : 0.f;
  float wx1 = ((unsigned)(xi + 1) <= 63u) ? fx : 0.f;
  float wy0 = ((unsigned)yi <= 63u) ? (1.f - fy) : 0.f;
  float wy1 = ((unsigned)(yi + 1) <= 63u) ? fy : 0.f;
  #pragma unroll
  for (int ci = 0; ci < 4; ++ci) {
    int c = cc * 4 + ci;
    const float* xp = x + (g * 64 + c) * HW;
    float vsum = wy0 * (wx0 * xp[y0c * 64 + x0c] + wx1 * xp[y0c * 64 + x1c]) +
                 wy1 * (wx0 * xp[y1c * 64 + x0c] + wx1 * xp[y1c * 64 + x1c]);
    xs[(g * 64 + c) * HW + n] = vsum;
  }
}

// ---- build 4-corner bf16-packed, zero-padded, log2e-scaled RPE tables ----
__global__ __launch_bounds__(256) void build_rpe4_kernel(const float* __restrict__ rpe,
                                                         unsigned int* __restrict__ tab4) {
  int idx = blockIdx.x * 256 + threadIdx.x;
  if (idx >= 8 * 16641) return;
  int h = idx / 16641; int r = idx - h * 16641;
  int y = r / 129, x = r - y * 129;
  const float* tb = rpe + h * 16129;
  auto pad = [&](int yy, int xx) -> float {
    if (yy < 1 || yy > 127 || xx < 1 || xx > 127) return 0.f;
    return tb[(yy - 1) * 127 + (xx - 1)] * LOG2E;
  };
  unsigned int w0 = (unsigned int)bf16b(pad(y, x)) | ((unsigned int)bf16b(pad(y + 1, x)) << 16);
  unsigned int w1 = (unsigned int)bf16b(pad(y, x + 1)) | ((unsigned int)bf16b(pad(y + 1, x + 1)) << 16);
  u32x2 v = {w0, w1};
  *(u32x2*)(tab4 + (size_t)idx * 2) = v;
}

// ---- fused attention: both heads per block, shared addr math, trimmed live state ----
// K cross-iter prefetch only; V loaded at top of its own iteration (consumed at end).
// LDS: P_pack (loop) unioned with red_l/red_acc (epilogue), barrier-separated.
__global__ __launch_bounds__(256, 3) void attn_kernel(const unsigned short* __restrict__ qt,
                                                      const unsigned short* __restrict__ kt,
                                                      const unsigned short* __restrict__ vbuf,
                                                      const float* __restrict__ cxy,
                                                      const unsigned int* __restrict__ tab4,
                                                      float* __restrict__ att) {
  __shared__ __align__(16) unsigned char smem[16896];
  auto P_pack = reinterpret_cast<unsigned int(*)[4][16][20]>(smem);        // [2][4][16][20] = 10240B
  auto red_l = reinterpret_cast<float(*)[4][16]>(smem);                    // [2][4][16] = 512B
  auto red_acc = reinterpret_cast<float(*)[4][32][16]>(smem + 512);        // [2][4][32][16] = 16384B

  int tid = threadIdx.x;
  int w = tid >> 6;
  int l = tid & 63;
  int lm = l & 15;   // column: query m
  int lg = l >> 4;   // lane group
  int g = blockIdx.x >> 8;
  int mt = blockIdx.x & 255;
  int m0 = mt * 16;
  int m = m0 + lm;
  int xm = m & 63, ym = m >> 6;
  float ex = (xm + 0.5f) * (63.0f / 64.0f) - 31.5f;
  float ey = (ym + 0.5f) * (63.0f / 64.0f) - 31.5f;
  int h0 = g * 2;
  const char* tb0 = (const char*)tab4 + (size_t)h0 * 133128;
  const char* tb1 = tb0 + 133128;
  const float* cbase = cxy + (size_t)g * HW * 2;
  const unsigned short* v0row0 = vbuf + (size_t)(h0 * 32 + lm) * HW;
  const unsigned short* v0row1 = vbuf + (size_t)(h0 * 32 + 16 + lm) * HW;
  const unsigned short* v1row0 = vbuf + (size_t)((h0 + 1) * 32 + lm) * HW;
  const unsigned short* v1row1 = vbuf + (size_t)((h0 + 1) * 32 + 16 + lm) * HW;

  short8 qf0 = *(const short8*)(qt + ((size_t)(h0 * HW + m) * 32 + 8 * lg));
  short8 qf1 = *(const short8*)(qt + ((size_t)((h0 + 1) * HW + m) * 32 + 8 * lg));

  f32x4 o0A = {0.f, 0.f, 0.f, 0.f}, o0B = {0.f, 0.f, 0.f, 0.f};
  f32x4 o1A = {0.f, 0.f, 0.f, 0.f}, o1B = {0.f, 0.f, 0.f, 0.f};
  float l0 = 0.f, l1 = 0.f;

  // ---------------- prologue ----------------
  float bias0[8], bias1[8];
  float2 ccv[8];
  short8 k0a, k0b, k1a, k1b;

  {
    float2 cc0[8];
    #pragma unroll
    for (int i = 0; i < 8; ++i) {
      int nl = 16 * (i >> 2) + 4 * lg + (i & 3);
      cc0[i] = *(const float2*)(cbase + (size_t)(w * 32 + nl) * 2);
    }
    int n0 = w * 32;
    k0a = *(const short8*)(kt + ((size_t)(h0 * HW + n0 + lm) * 32 + 8 * lg));
    k0b = *(const short8*)(kt + ((size_t)(h0 * HW + n0 + 16 + lm) * 32 + 8 * lg));
    k1a = *(const short8*)(kt + ((size_t)((h0 + 1) * HW + n0 + lm) * 32 + 8 * lg));
    k1b = *(const short8*)(kt + ((size_t)((h0 + 1) * HW + n0 + 16 + lm) * 32 + 8 * lg));
    u32x2a t0[8], t1[8];
    float fxs[8], fys[8];
    #pragma unroll
    for (int i = 0; i < 8; ++i) {
      float gx = ex + cc0[i].x, gy = ey + cc0[i].y;
      float xf = floorf(gx), yf = floorf(gy);
      fxs[i] = gx - xf; fys[i] = gy - yf;
      unsigned off = (unsigned)((int)yf * 1032 + ((int)xf << 3));
      t0[i] = *(const u32x2a*)(tb0 + off);
      t1[i] = *(const u32x2a*)(tb1 + off);
    }
    #pragma unroll
    for (int i = 0; i < 8; ++i) {
      int nl = 16 * (i >> 2) + 4 * lg + (i & 3);
      ccv[i] = *(const float2*)(cbase + (size_t)(128 + w * 32 + nl) * 2);
    }
    #pragma unroll
    for (int i = 0; i < 8; ++i) {
      float a00 = __uint_as_float(t0[i][0] << 16);
      float a10 = __uint_as_float(t0[i][0] & 0xffff0000u);
      float a01 = __uint_as_float(t0[i][1] << 16);
      float a11 = __uint_as_float(t0[i][1] & 0xffff0000u);
      float ly0 = a00 + fys[i] * (a10 - a00);
      float ly1 = a01 + fys[i] * (a11 - a01);
      bias0[i] = ly0 + fxs[i] * (ly1 - ly0);
      float b00 = __uint_as_float(t1[i][0] << 16);
      float b10 = __uint_as_float(t1[i][0] & 0xffff0000u);
      float b01 = __uint_as_float(t1[i][1] << 16);
      float b11 = __uint_as_float(t1[i][1] & 0xffff0000u);
      float my0 = b00 + fys[i] * (b10 - b00);
      float my1 = b01 + fys[i] * (b11 - b01);
      bias1[i] = my0 + fxs[i] * (my1 - my0);
    }
  }

  // ---------------- main loop ----------------
  for (int it = 0; it < 32; ++it) {
    int n0 = it * 128 + w * 32;
    // V for CURRENT iteration: issued now, consumed after softmax (~400cy later)
    short8 v0a = *(const short8*)(v0row0 + n0 + 8 * lg);
    short8 v0b = *(const short8*)(v0row1 + n0 + 8 * lg);
    short8 v1a = *(const short8*)(v1row0 + n0 + 8 * lg);
    short8 v1b = *(const short8*)(v1row1 + n0 + 8 * lg);

    f32x4 z = {0.f, 0.f, 0.f, 0.f};
    f32x4 s0a = __builtin_amdgcn_mfma_f32_16x16x32_bf16(k0a, qf0, z, 0, 0, 0);
    f32x4 s0b = __builtin_amdgcn_mfma_f32_16x16x32_bf16(k0b, qf0, z, 0, 0, 0);
    f32x4 s1a = __builtin_amdgcn_mfma_f32_16x16x32_bf16(k1a, qf1, z, 0, 0, 0);
    f32x4 s1b = __builtin_amdgcn_mfma_f32_16x16x32_bf16(k1b, qf1, z, 0, 0, 0);

    // prefetch K for it+1 (both heads)
    int n0n = ((it + 1) & 31) * 128 + w * 32;
    short8 k0an = *(const short8*)(kt + ((size_t)(h0 * HW + n0n + lm) * 32 + 8 * lg));
    short8 k0bn = *(const short8*)(kt + ((size_t)(h0 * HW + n0n + 16 + lm) * 32 + 8 * lg));
    short8 k1an = *(const short8*)(kt + ((size_t)((h0 + 1) * HW + n0n + lm) * 32 + 8 * lg));
    short8 k1bn = *(const short8*)(kt + ((size_t)((h0 + 1) * HW + n0n + 16 + lm) * 32 + 8 * lg));

    // table gathers for it+1 (shared address, two tables)
    u32x2a t0[8], t1[8];
    float fxs[8], fys[8];
    #pragma unroll
    for (int i = 0; i < 8; ++i) {
      float gx = ex + ccv[i].x, gy = ey + ccv[i].y;
      float xf = floorf(gx), yf = floorf(gy);
      fxs[i] = gx - xf; fys[i] = gy - yf;
      unsigned off = (unsigned)((int)yf * 1032 + ((int)xf << 3));
      t0[i] = *(const u32x2a*)(tb0 + off);
      t1[i] = *(const u32x2a*)(tb1 + off);
    }
    // cxy for it+2
    int n0n2 = ((it + 2) & 31) * 128 + w * 32;
    float2 ccn[8];
    #pragma unroll
    for (int i = 0; i < 8; ++i) {
      int nl = 16 * (i >> 2) + 4 * lg + (i & 3);
      ccn[i] = *(const float2*)(cbase + (size_t)(n0n2 + nl) * 2);
    }

    // softmax for it (both heads)
    float p0[8], p1[8];
    #pragma unroll
    for (int i = 0; i < 8; ++i) {
      float q0 = (i < 4) ? s0a[i & 3] : s0b[i & 3];
      float q1 = (i < 4) ? s1a[i & 3] : s1b[i & 3];
      p0[i] = __builtin_amdgcn_exp2f(q0 + bias0[i]);
      p1[i] = __builtin_amdgcn_exp2f(q1 + bias1[i]);
    }
    l0 += ((p0[0] + p0[1]) + (p0[2] + p0[3])) + ((p0[4] + p0[5]) + (p0[6] + p0[7]));
    l1 += ((p1[0] + p1[1]) + (p1[2] + p1[3])) + ((p1[4] + p1[5]) + (p1[6] + p1[7]));
    {
      unsigned int w0 = (unsigned int)bf16b(p0[0]) | ((unsigned int)bf16b(p0[1]) << 16);
      unsigned int w1 = (unsigned int)bf16b(p0[2]) | ((unsigned int)bf16b(p0[3]) << 16);
      unsigned int w2 = (unsigned int)bf16b(p0[4]) | ((unsigned int)bf16b(p0[5]) << 16);
      unsigned int w3 = (unsigned int)bf16b(p0[6]) | ((unsigned int)bf16b(p0[7]) << 16);
      u32x2 wa = {w0, w1}, wb = {w2, w3};
      *(u32x2*)&P_pack[0][w][lm][2 * lg] = wa;
      *(u32x2*)&P_pack[0][w][lm][8 + 2 * lg] = wb;
    }
    {
      unsigned int w0 = (unsigned int)bf16b(p1[0]) | ((unsigned int)bf16b(p1[1]) << 16);
      unsigned int w1 = (unsigned int)bf16b(p1[2]) | ((unsigned int)bf16b(p1[3]) << 16);
      unsigned int w2 = (unsigned int)bf16b(p1[4]) | ((unsigned int)bf16b(p1[5]) << 16);
      unsigned int w3 = (unsigned int)bf16b(p1[6]) | ((unsigned int)bf16b(p1[7]) << 16);
      u32x2 wa = {w0, w1}, wb = {w2, w3};
      *(u32x2*)&P_pack[1][w][lm][2 * lg] = wa;
      *(u32x2*)&P_pack[1][w][lm][8 + 2 * lg] = wb;
    }
    {
      u32x4 pw0 = *(u32x4*)&P_pack[0][w][lm][4 * lg];
      union { u32x4 u; short8 s; } c0; c0.u = pw0;
      o0A = __builtin_amdgcn_mfma_f32_16x16x32_bf16(v0a, c0.s, o0A, 0, 0, 0);
      o0B = __builtin_amdgcn_mfma_f32_16x16x32_bf16(v0b, c0.s, o0B, 0, 0, 0);
      u32x4 pw1 = *(u32x4*)&P_pack[1][w][lm][4 * lg];
      union { u32x4 u; short8 s; } c1; c1.u = pw1;
      o1A = __builtin_amdgcn_mfma_f32_16x16x32_bf16(v1a, c1.s, o1A, 0, 0, 0);
      o1B = __builtin_amdgcn_mfma_f32_16x16x32_bf16(v1b, c1.s, o1B, 0, 0, 0);
    }

    // finish bias for it+1 (both heads)
    #pragma unroll
    for (int i = 0; i < 8; ++i) {
      float a00 = __uint_as_float(t0[i][0] << 16);
      float a10 = __uint_as_float(t0[i][0] & 0xffff0000u);
      float a01 = __uint_as_float(t0[i][1] << 16);
      float a11 = __uint_as_float(t0[i][1] & 0xffff0000u);
      float ly0 = a00 + fys[i] * (a10 - a00);
      float ly1 = a01 + fys[i] * (a11 - a01);
      bias0[i] = ly0 + fxs[i] * (ly1 - ly0);
      float b00 = __uint_as_float(t1[i][0] << 16);
      float b10 = __uint_as_float(t1[i][0] & 0xffff0000u);
      float b01 = __uint_as_float(t1[i][1] << 16);
      float b11 = __uint_as_float(t1[i][1] & 0xffff0000u);
      float my0 = b00 + fys[i] * (b10 - b00);
      float my1 = b01 + fys[i] * (b11 - b01);
      bias1[i] = my0 + fxs[i] * (my1 - my0);
    }
    k0a = k0an; k0b = k0bn;
    k1a = k1an; k1b = k1bn;
    #pragma unroll
    for (int i = 0; i < 8; ++i) ccv[i] = ccn[i];
  }

  // ---------------- epilogue: cross-wave merge (LDS reused; barrier-separated) ----------------
  __syncthreads();   // all waves done with P_pack before red_* overwrite it
  l0 += __shfl_xor(l0, 16); l0 += __shfl_xor(l0, 32);
  l1 += __shfl_xor(l1, 16); l1 += __shfl_xor(l1, 32);
  if (lg == 0) { red_l[0][w][lm] = l0; red_l[1][w][lm] = l1; }
  #pragma unroll
  for (int r = 0; r < 4; ++r) {
    red_acc[0][w][4 * lg + r][lm] = o0A[r];
    red_acc[0][w][16 + 4 * lg + r][lm] = o0B[r];
    red_acc[1][w][4 * lg + r][lm] = o1A[r];
    red_acc[1][w][16 + 4 * lg + r][lm] = o1B[r];
  }
  __syncthreads();
  #pragma unroll
  for (int rep = 0; rep < 8; ++rep) {
    int idx = tid + rep * 256;   // hh*1024 + cl*16 + mm
    int hh = idx >> 10, cl = (idx >> 4) & 31, mm = idx & 15;
    float lsum = 0.f, osum = 0.f;
    #pragma unroll
    for (int ww = 0; ww < 4; ++ww) {
      lsum += red_l[hh][ww][mm];
      osum += red_acc[hh][ww][cl][mm];
    }
    att[(size_t)((h0 + hh) * 32 + cl) * HW + m0 + mm] = osum / lsum;
  }
}

extern "C" void kernel_launch(void* const* d_in, const int* in_sizes, int n_in,
                              void* d_out, int out_size, void* d_ws, size_t ws_size,
                              hipStream_t stream) {
  const float* x    = (const float*)d_in[0];
  const float* wq   = (const float*)d_in[1];
  const float* bq   = (const float*)d_in[2];
  const float* wk   = (const float*)d_in[3];
  const float* bk   = (const float*)d_in[4];
  const float* wv   = (const float*)d_in[5];
  const float* bv   = (const float*)d_in[6];
  const float* wdw  = (const float*)d_in[7];
  const float* bdw  = (const float*)d_in[8];
  const float* lng  = (const float*)d_in[9];
  const float* lnb  = (const float*)d_in[10];
  const float* wpw  = (const float*)d_in[11];
  const float* rpe  = (const float*)d_in[12];
  const float* wout = (const float*)d_in[13];
  const float* bout = (const float*)d_in[14];
  float* out = (float*)d_out;

  float* ws = (float*)d_ws;
  float* q_f32 = ws;                                        // 4MB (reused as xs)
  float* o_f32 = ws + (1 << 20);                            // 4MB (reused as att)
  unsigned short* qt  = (unsigned short*)(ws + (2 << 20));  // 2MB
  unsigned short* ktp = (unsigned short*)(ws + ((2 << 20) + (1 << 19)));  // 2MB
  unsigned short* vbp = (unsigned short*)(ws + (3 << 20));  // 2MB
  float* pos  = ws + ((3 << 20) + (1 << 19));               // 128KB
  float* cxy  = pos + 32768;                                // 128KB
  unsigned int* tab4 = (unsigned int*)(cxy + 32768);        // 1.06MB

  gemm256<<<512, 256, 0, stream>>>(wq, bq, x, q_f32, qt, SCALE * LOG2E);
  build_rpe4_kernel<<<521, 256, 0, stream>>>(rpe, tab4);
  dwconv_kernel<<<512, 256, 0, stream>>>(q_f32, wdw, bdw, o_f32);
  ln_offset_kernel<<<4096, 256, 0, stream>>>(o_f32, lng, lnb, wpw, pos, cxy);
  sample_kernel<<<1024, 256, 0, stream>>>(x, pos, q_f32);   // q_f32 := xs
  gemm_kv<<<512, 256, 0, stream>>>(wk, bk, wv, bv, q_f32, ktp, vbp);
  attn_kernel<<<1024, 256, 0, stream>>>(qt, ktp, vbp, cxy, tab4, o_f32);  // o_f32 := att
  gemm256<<<512, 256, 0, stream>>>(wout, bout, o_f32, out, nullptr, 1.0f);
}

// Round 21
// 274.833 us; speedup vs baseline: 1.0927x; 1.0046x over previous
//
#include <hip/hip_runtime.h>
#include <hip/hip_bf16.h>
#include <math.h>

#define HW 4096
#define SCALE 0.17677669529663687f
#define LOG2E 1.4426950408889634f

typedef __attribute__((ext_vector_type(8))) short short8;
typedef __attribute__((ext_vector_type(4))) float f32x4;
typedef __attribute__((ext_vector_type(4))) unsigned int u32x4;
typedef __attribute__((ext_vector_type(2))) unsigned int u32x2;
typedef __attribute__((ext_vector_type(2), aligned(8))) unsigned int u32x2a;

static __device__ __forceinline__ unsigned short bf16b(float f) {
  __hip_bfloat16 h = __float2bfloat16(f);
  return *reinterpret_cast<unsigned short*>(&h);
}

// ---- GEMM: Y[256][4096] = W @ X + b. 1 px/thread, o-tile 8, grid 512 (2 blocks/CU).
__global__ __launch_bounds__(256) void gemm256(const float* __restrict__ W,
                                               const float* __restrict__ bias,
                                               const float* __restrict__ X,
                                               float* __restrict__ Yf,
                                               unsigned short* __restrict__ Yt,
                                               float sc) {
  int tid = threadIdx.x;
  int o0 = (blockIdx.x >> 4) * 8;          // 32 o-groups
  int p = (blockIdx.x & 15) * 256 + tid;   // 16 p-tiles of 256
  const float* Wb = W + o0 * 256;
  float acc[8];
  #pragma unroll
  for (int i = 0; i < 8; ++i) acc[i] = 0.f;
  #pragma unroll 8
  for (int c = 0; c < 256; ++c) {
    float xv = X[c * HW + p];
    #pragma unroll
    for (int i = 0; i < 8; ++i) acc[i] += Wb[i * 256 + c] * xv;
  }
  float r[8];
  #pragma unroll
  for (int i = 0; i < 8; ++i) r[i] = acc[i] + bias[o0 + i];
  if (Yf) {
    #pragma unroll
    for (int i = 0; i < 8; ++i) Yf[(size_t)(o0 + i) * HW + p] = r[i];
  }
  if (Yt) {
    int h = o0 >> 5, c0 = o0 & 31;
    u32x4 pk;
    #pragma unroll
    for (int j = 0; j < 4; ++j)
      pk[j] = (unsigned int)bf16b(r[2 * j] * sc) | ((unsigned int)bf16b(r[2 * j + 1] * sc) << 16);
    *(u32x4*)(Yt + ((size_t)(h * HW + p) * 32 + c0)) = pk;
  }
}

// ---- fused K+V projection, 1 px/thread, grid 512 ----
__global__ __launch_bounds__(256) void gemm_kv(const float* __restrict__ Wk,
                                               const float* __restrict__ bk,
                                               const float* __restrict__ Wv,
                                               const float* __restrict__ bv,
                                               const float* __restrict__ X,
                                               unsigned short* __restrict__ Yt,
                                               unsigned short* __restrict__ Yv) {
  int tid = threadIdx.x;
  int o0 = (blockIdx.x >> 4) * 8;
  int p = (blockIdx.x & 15) * 256 + tid;
  const float* Wkb = Wk + o0 * 256;
  const float* Wvb = Wv + o0 * 256;
  float ka[8], va[8];
  #pragma unroll
  for (int i = 0; i < 8; ++i) { ka[i] = 0.f; va[i] = 0.f; }
  #pragma unroll 4
  for (int c = 0; c < 256; ++c) {
    float xv = X[c * HW + p];
    #pragma unroll
    for (int i = 0; i < 8; ++i) {
      ka[i] += Wkb[i * 256 + c] * xv;
      va[i] += Wvb[i * 256 + c] * xv;
    }
  }
  {
    int h = o0 >> 5, c0 = o0 & 31;
    u32x4 pk;
    #pragma unroll
    for (int j = 0; j < 4; ++j) {
      float k0 = ka[2 * j] + bk[o0 + 2 * j];
      float k1 = ka[2 * j + 1] + bk[o0 + 2 * j + 1];
      pk[j] = (unsigned int)bf16b(k0) | ((unsigned int)bf16b(k1) << 16);
    }
    *(u32x4*)(Yt + ((size_t)(h * HW + p) * 32 + c0)) = pk;
  }
  #pragma unroll
  for (int i = 0; i < 8; ++i)
    Yv[(size_t)(o0 + i) * HW + p] = bf16b(va[i] + bv[o0 + i]);
}

// ---- depthwise 9x9 conv: 8 y-outputs per thread, 16-row sliding window ----
__global__ __launch_bounds__(256) void dwconv_kernel(const float* __restrict__ q,
                                                     const float* __restrict__ wdw,
                                                     const float* __restrict__ bdw,
                                                     float* __restrict__ o) {
  int x = threadIdx.x & 63;
  int w = threadIdx.x >> 6;
  int bid = blockIdx.x;               // g*128 + c*2 + half
  int half = bid & 1; int c = (bid >> 1) & 63; int g = bid >> 7;
  int y0 = half * 32 + w * 8;
  const float* qc = q + (g * 64 + c) * HW;
  const float* wc = wdw + c * 81;
  float b = bdw[c];
  float acc[8];
  #pragma unroll
  for (int i = 0; i < 8; ++i) acc[i] = b;
  #pragma unroll
  for (int r = 0; r < 16; ++r) {
    int yy = y0 - 4 + r;
    bool rowok = (unsigned)yy <= 63u;
    int yc = min(max(yy, 0), 63);
    float v[9];
    #pragma unroll
    for (int kx = 0; kx < 9; ++kx) {
      int xx = x + kx - 4;
      bool ok = rowok && ((unsigned)xx <= 63u);
      int xc = min(max(xx, 0), 63);
      float lv = qc[yc * 64 + xc];
      v[kx] = ok ? lv : 0.f;
    }
    #pragma unroll
    for (int oy = 0; oy < 8; ++oy) {
      int ky = r - oy;
      if (ky < 0 || ky > 8) continue;
      #pragma unroll
      for (int kx = 0; kx < 9; ++kx)
        acc[oy] += wc[ky * 9 + kx] * v[kx];
    }
  }
  #pragma unroll
  for (int oy = 0; oy < 8; ++oy)
    o[(g * 64 + c) * HW + (y0 + oy) * 64 + x] = acc[oy];
}

// ---- LN + GELU + pointwise + tanh -> pos/cxy (shuffle version, grid 4096) ----
__global__ __launch_bounds__(256) void ln_offset_kernel(const float* __restrict__ o,
                                                        const float* __restrict__ ln_g,
                                                        const float* __restrict__ ln_b,
                                                        const float* __restrict__ wpw,
                                                        float* __restrict__ pos,
                                                        float* __restrict__ cxy) {
  int wave = threadIdx.x >> 6;
  int c = threadIdx.x & 63;
  int bid = blockIdx.x;
  int xc = bid & 15; int y = (bid >> 4) & 63; int g = bid >> 10;
  int x = xc * 4 + wave;
  int p = y * 64 + x;
  float v = o[(g * 64 + c) * HW + p];
  float s = v, s2 = v * v;
  #pragma unroll
  for (int m = 32; m; m >>= 1) { s += __shfl_xor(s, m); s2 += __shfl_xor(s2, m); }
  float mu = s * (1.f / 64.f);
  float var = s2 * (1.f / 64.f) - mu * mu;
  float nv = (v - mu) * rsqrtf(var + 1e-5f) * ln_g[c] + ln_b[c];
  nv = 0.5f * nv * (1.f + erff(nv * 0.70710678118654752f));
  float t0 = wpw[c] * nv, t1 = wpw[64 + c] * nv;
  #pragma unroll
  for (int m = 32; m; m >>= 1) { t0 += __shfl_xor(t0, m); t1 += __shfl_xor(t1, m); }
  if (c == 0) {
    float offy = tanhf(t0) * (2.0f / 64.0f);
    float offx = tanhf(t1) * (2.0f / 64.0f);
    float py = offy + (y + 0.5f) * (2.f / 64.f) - 1.f;
    float px = offx + (x + 0.5f) * (2.f / 64.f) - 1.f;
    pos[(g * HW + p) * 2 + 0] = py;
    pos[(g * HW + p) * 2 + 1] = px;
    cxy[(g * HW + p) * 2 + 0] = 64.0f - 31.5f * px;
    cxy[(g * HW + p) * 2 + 1] = 64.0f - 31.5f * py;
  }
}

// ---- bilinear sample of x at pos -> xs[256][4096]; 4 channels/thread, grid 1024 ----
__global__ __launch_bounds__(256) void sample_kernel(const float* __restrict__ x,
                                                     const float* __restrict__ pos,
                                                     float* __restrict__ xs) {
  int bid = blockIdx.x;  // g*256 + nt*16 + cc
  int cc = bid & 15; int nt = (bid >> 4) & 15; int g = bid >> 8;
  int n = nt * 256 + threadIdx.x;
  float py = pos[(g * HW + n) * 2 + 0];
  float px = pos[(g * HW + n) * 2 + 1];
  float gx = (px + 1.f) * 31.5f;
  float gy = (py + 1.f) * 31.5f;
  float xf = floorf(gx), yf = floorf(gy);
  int xi = (int)xf, yi = (int)yf;
  float fx = gx - xf, fy = gy - yf;
  int x0c = min(max(xi, 0), 63), x1c = min(max(xi + 1, 0), 63);
  int y0c = min(max(yi, 0), 63), y1c = min(max(yi + 1, 0), 63);
  float wx0 = ((unsigned)xi <= 63u) ? (1.f - fx) : 0.f;
  float wx1 = ((unsigned)(xi + 1) <= 63u) ? fx : 0.f;
  float wy0 = ((unsigned)yi <= 63u) ? (1.f - fy) : 0.f;
  float wy1 = ((unsigned)(yi + 1) <= 63u) ? fy : 0.f;
  #pragma unroll
  for (int ci = 0; ci < 4; ++ci) {
    int c = cc * 4 + ci;
    const float* xp = x + (g * 64 + c) * HW;
    float vsum = wy0 * (wx0 * xp[y0c * 64 + x0c] + wx1 * xp[y0c * 64 + x1c]) +
                 wy1 * (wx0 * xp[y1c * 64 + x0c] + wx1 * xp[y1c * 64 + x1c]);
    xs[(g * 64 + c) * HW + n] = vsum;
  }
}

// ---- build 4-corner bf16-packed, zero-padded, log2e-scaled RPE tables ----
__global__ __launch_bounds__(256) void build_rpe4_kernel(const float* __restrict__ rpe,
                                                         unsigned int* __restrict__ tab4) {
  int idx = blockIdx.x * 256 + threadIdx.x;
  if (idx >= 8 * 16641) return;
  int h = idx / 16641; int r = idx - h * 16641;
  int y = r / 129, x = r - y * 129;
  const float* tb = rpe + h * 16129;
  auto pad = [&](int yy, int xx) -> float {
    if (yy < 1 || yy > 127 || xx < 1 || xx > 127) return 0.f;
    return tb[(yy - 1) * 127 + (xx - 1)] * LOG2E;
  };
  unsigned int w0 = (unsigned int)bf16b(pad(y, x)) | ((unsigned int)bf16b(pad(y + 1, x)) << 16);
  unsigned int w1 = (unsigned int)bf16b(pad(y, x + 1)) | ((unsigned int)bf16b(pad(y + 1, x + 1)) << 16);
  u32x2 v = {w0, w1};
  *(u32x2*)(tab4 + (size_t)idx * 2) = v;
}

// ---- fused attention: both heads/block, 8 waves (512 thr), 16 n-iters per wave ----
__global__ __launch_bounds__(512, 2) void attn_kernel(const unsigned short* __restrict__ qt,
                                                      const unsigned short* __restrict__ kt,
                                                      const unsigned short* __restrict__ vbuf,
                                                      const float* __restrict__ cxy,
                                                      const unsigned int* __restrict__ tab4,
                                                      float* __restrict__ att) {
  __shared__ __align__(16) unsigned char smem[33792];
  auto P_pack = reinterpret_cast<unsigned int(*)[8][16][20]>(smem);        // [2][8][16][20] = 20480B
  auto red_l = reinterpret_cast<float(*)[8][16]>(smem);                    // [2][8][16] = 1024B
  auto red_acc = reinterpret_cast<float(*)[8][32][16]>(smem + 1024);       // [2][8][32][16] = 32768B

  int tid = threadIdx.x;
  int w = tid >> 6;      // 8 waves
  int l = tid & 63;
  int lm = l & 15;       // column: query m
  int lg = l >> 4;       // lane group
  int g = blockIdx.x >> 8;
  int mt = blockIdx.x & 255;
  int m0 = mt * 16;
  int m = m0 + lm;
  int xm = m & 63, ym = m >> 6;
  float ex = (xm + 0.5f) * (63.0f / 64.0f) - 31.5f;
  float ey = (ym + 0.5f) * (63.0f / 64.0f) - 31.5f;
  int h0 = g * 2;
  const char* tb0 = (const char*)tab4 + (size_t)h0 * 133128;
  const char* tb1 = tb0 + 133128;
  const float* cbase = cxy + (size_t)g * HW * 2;
  const unsigned short* v0row0 = vbuf + (size_t)(h0 * 32 + lm) * HW;
  const unsigned short* v0row1 = vbuf + (size_t)(h0 * 32 + 16 + lm) * HW;
  const unsigned short* v1row0 = vbuf + (size_t)((h0 + 1) * 32 + lm) * HW;
  const unsigned short* v1row1 = vbuf + (size_t)((h0 + 1) * 32 + 16 + lm) * HW;

  short8 qf0 = *(const short8*)(qt + ((size_t)(h0 * HW + m) * 32 + 8 * lg));
  short8 qf1 = *(const short8*)(qt + ((size_t)((h0 + 1) * HW + m) * 32 + 8 * lg));

  f32x4 o0A = {0.f, 0.f, 0.f, 0.f}, o0B = {0.f, 0.f, 0.f, 0.f};
  f32x4 o1A = {0.f, 0.f, 0.f, 0.f}, o1B = {0.f, 0.f, 0.f, 0.f};
  float l0 = 0.f, l1 = 0.f;

  // ---------------- prologue ----------------
  float bias0[8], bias1[8];
  float2 ccv[8];
  short8 k0a, k0b, k1a, k1b;

  {
    float2 cc0[8];
    #pragma unroll
    for (int i = 0; i < 8; ++i) {
      int nl = 16 * (i >> 2) + 4 * lg + (i & 3);
      cc0[i] = *(const float2*)(cbase + (size_t)(w * 32 + nl) * 2);
    }
    int n0 = w * 32;
    k0a = *(const short8*)(kt + ((size_t)(h0 * HW + n0 + lm) * 32 + 8 * lg));
    k0b = *(const short8*)(kt + ((size_t)(h0 * HW + n0 + 16 + lm) * 32 + 8 * lg));
    k1a = *(const short8*)(kt + ((size_t)((h0 + 1) * HW + n0 + lm) * 32 + 8 * lg));
    k1b = *(const short8*)(kt + ((size_t)((h0 + 1) * HW + n0 + 16 + lm) * 32 + 8 * lg));
    u32x2a t0[8], t1[8];
    float fxs[8], fys[8];
    #pragma unroll
    for (int i = 0; i < 8; ++i) {
      float gx = ex + cc0[i].x, gy = ey + cc0[i].y;
      float xf = floorf(gx), yf = floorf(gy);
      fxs[i] = gx - xf; fys[i] = gy - yf;
      unsigned off = (unsigned)((int)yf * 1032 + ((int)xf << 3));
      t0[i] = *(const u32x2a*)(tb0 + off);
      t1[i] = *(const u32x2a*)(tb1 + off);
    }
    #pragma unroll
    for (int i = 0; i < 8; ++i) {
      int nl = 16 * (i >> 2) + 4 * lg + (i & 3);
      ccv[i] = *(const float2*)(cbase + (size_t)(256 + w * 32 + nl) * 2);
    }
    #pragma unroll
    for (int i = 0; i < 8; ++i) {
      float a00 = __uint_as_float(t0[i][0] << 16);
      float a10 = __uint_as_float(t0[i][0] & 0xffff0000u);
      float a01 = __uint_as_float(t0[i][1] << 16);
      float a11 = __uint_as_float(t0[i][1] & 0xffff0000u);
      float ly0 = a00 + fys[i] * (a10 - a00);
      float ly1 = a01 + fys[i] * (a11 - a01);
      bias0[i] = ly0 + fxs[i] * (ly1 - ly0);
      float b00 = __uint_as_float(t1[i][0] << 16);
      float b10 = __uint_as_float(t1[i][0] & 0xffff0000u);
      float b01 = __uint_as_float(t1[i][1] << 16);
      float b11 = __uint_as_float(t1[i][1] & 0xffff0000u);
      float my0 = b00 + fys[i] * (b10 - b00);
      float my1 = b01 + fys[i] * (b11 - b01);
      bias1[i] = my0 + fxs[i] * (my1 - my0);
    }
  }

  // ---------------- main loop: 16 iterations, n-tiles strided by 256 ----------------
  for (int it = 0; it < 16; ++it) {
    int n0 = it * 256 + w * 32;
    // V for CURRENT iteration (consumed after softmax)
    short8 v0a = *(const short8*)(v0row0 + n0 + 8 * lg);
    short8 v0b = *(const short8*)(v0row1 + n0 + 8 * lg);
    short8 v1a = *(const short8*)(v1row0 + n0 + 8 * lg);
    short8 v1b = *(const short8*)(v1row1 + n0 + 8 * lg);

    f32x4 z = {0.f, 0.f, 0.f, 0.f};
    f32x4 s0a = __builtin_amdgcn_mfma_f32_16x16x32_bf16(k0a, qf0, z, 0, 0, 0);
    f32x4 s0b = __builtin_amdgcn_mfma_f32_16x16x32_bf16(k0b, qf0, z, 0, 0, 0);
    f32x4 s1a = __builtin_amdgcn_mfma_f32_16x16x32_bf16(k1a, qf1, z, 0, 0, 0);
    f32x4 s1b = __builtin_amdgcn_mfma_f32_16x16x32_bf16(k1b, qf1, z, 0, 0, 0);

    // prefetch K for it+1
    int n0n = ((it + 1) & 15) * 256 + w * 32;
    short8 k0an = *(const short8*)(kt + ((size_t)(h0 * HW + n0n + lm) * 32 + 8 * lg));
    short8 k0bn = *(const short8*)(kt + ((size_t)(h0 * HW + n0n + 16 + lm) * 32 + 8 * lg));
    short8 k1an = *(const short8*)(kt + ((size_t)((h0 + 1) * HW + n0n + lm) * 32 + 8 * lg));
    short8 k1bn = *(const short8*)(kt + ((size_t)((h0 + 1) * HW + n0n + 16 + lm) * 32 + 8 * lg));

    // table gathers for it+1 (shared address, two tables)
    u32x2a t0[8], t1[8];
    float fxs[8], fys[8];
    #pragma unroll
    for (int i = 0; i < 8; ++i) {
      float gx = ex + ccv[i].x, gy = ey + ccv[i].y;
      float xf = floorf(gx), yf = floorf(gy);
      fxs[i] = gx - xf; fys[i] = gy - yf;
      unsigned off = (unsigned)((int)yf * 1032 + ((int)xf << 3));
      t0[i] = *(const u32x2a*)(tb0 + off);
      t1[i] = *(const u32x2a*)(tb1 + off);
    }
    // cxy for it+2
    int n0n2 = ((it + 2) & 15) * 256 + w * 32;
    float2 ccn[8];
    #pragma unroll
    for (int i = 0; i < 8; ++i) {
      int nl = 16 * (i >> 2) + 4 * lg + (i & 3);
      ccn[i] = *(const float2*)(cbase + (size_t)(n0n2 + nl) * 2);
    }

    // softmax for it (both heads)
    float p0[8], p1[8];
    #pragma unroll
    for (int i = 0; i < 8; ++i) {
      float q0 = (i < 4) ? s0a[i & 3] : s0b[i & 3];
      float q1 = (i < 4) ? s1a[i & 3] : s1b[i & 3];
      p0[i] = __builtin_amdgcn_exp2f(q0 + bias0[i]);
      p1[i] = __builtin_amdgcn_exp2f(q1 + bias1[i]);
    }
    l0 += ((p0[0] + p0[1]) + (p0[2] + p0[3])) + ((p0[4] + p0[5]) + (p0[6] + p0[7]));
    l1 += ((p1[0] + p1[1]) + (p1[2] + p1[3])) + ((p1[4] + p1[5]) + (p1[6] + p1[7]));
    {
      unsigned int w0 = (unsigned int)bf16b(p0[0]) | ((unsigned int)bf16b(p0[1]) << 16);
      unsigned int w1 = (unsigned int)bf16b(p0[2]) | ((unsigned int)bf16b(p0[3]) << 16);
      unsigned int w2 = (unsigned int)bf16b(p0[4]) | ((unsigned int)bf16b(p0[5]) << 16);
      unsigned int w3 = (unsigned int)bf16b(p0[6]) | ((unsigned int)bf16b(p0[7]) << 16);
      u32x2 wa = {w0, w1}, wb = {w2, w3};
      *(u32x2*)&P_pack[0][w][lm][2 * lg] = wa;
      *(u32x2*)&P_pack[0][w][lm][8 + 2 * lg] = wb;
    }
    {
      unsigned int w0 = (unsigned int)bf16b(p1[0]) | ((unsigned int)bf16b(p1[1]) << 16);
      unsigned int w1 = (unsigned int)bf16b(p1[2]) | ((unsigned int)bf16b(p1[3]) << 16);
      unsigned int w2 = (unsigned int)bf16b(p1[4]) | ((unsigned int)bf16b(p1[5]) << 16);
      unsigned int w3 = (unsigned int)bf16b(p1[6]) | ((unsigned int)bf16b(p1[7]) << 16);
      u32x2 wa = {w0, w1}, wb = {w2, w3};
      *(u32x2*)&P_pack[1][w][lm][2 * lg] = wa;
      *(u32x2*)&P_pack[1][w][lm][8 + 2 * lg] = wb;
    }
    {
      u32x4 pw0 = *(u32x4*)&P_pack[0][w][lm][4 * lg];
      union { u32x4 u; short8 s; } c0; c0.u = pw0;
      o0A = __builtin_amdgcn_mfma_f32_16x16x32_bf16(v0a, c0.s, o0A, 0, 0, 0);
      o0B = __builtin_amdgcn_mfma_f32_16x16x32_bf16(v0b, c0.s, o0B, 0, 0, 0);
      u32x4 pw1 = *(u32x4*)&P_pack[1][w][lm][4 * lg];
      union { u32x4 u; short8 s; } c1; c1.u = pw1;
      o1A = __builtin_amdgcn_mfma_f32_16x16x32_bf16(v1a, c1.s, o1A, 0, 0, 0);
      o1B = __builtin_amdgcn_mfma_f32_16x16x32_bf16(v1b, c1.s, o1B, 0, 0, 0);
    }

    // finish bias for it+1 (both heads)
    #pragma unroll
    for (int i = 0; i < 8; ++i) {
      float a00 = __uint_as_float(t0[i][0] << 16);
      float a10 = __uint_as_float(t0[i][0] & 0xffff0000u);
      float a01 = __uint_as_float(t0[i][1] << 16);
      float a11 = __uint_as_float(t0[i][1] & 0xffff0000u);
      float ly0 = a00 + fys[i] * (a10 - a00);
      float ly1 = a01 + fys[i] * (a11 - a01);
      bias0[i] = ly0 + fxs[i] * (ly1 - ly0);
      float b00 = __uint_as_float(t1[i][0] << 16);
      float b10 = __uint_as_float(t1[i][0] & 0xffff0000u);
      float b01 = __uint_as_float(t1[i][1] << 16);
      float b11 = __uint_as_float(t1[i][1] & 0xffff0000u);
      float my0 = b00 + fys[i] * (b10 - b00);
      float my1 = b01 + fys[i] * (b11 - b01);
      bias1[i] = my0 + fxs[i] * (my1 - my0);
    }
    k0a = k0an; k0b = k0bn;
    k1a = k1an; k1b = k1bn;
    #pragma unroll
    for (int i = 0; i < 8; ++i) ccv[i] = ccn[i];
  }

  // ---------------- epilogue: cross-wave merge over 8 waves ----------------
  __syncthreads();   // all waves done with P_pack before red_* overwrite it
  l0 += __shfl_xor(l0, 16); l0 += __shfl_xor(l0, 32);
  l1 += __shfl_xor(l1, 16); l1 += __shfl_xor(l1, 32);
  if (lg == 0) { red_l[0][w][lm] = l0; red_l[1][w][lm] = l1; }
  #pragma unroll
  for (int r = 0; r < 4; ++r) {
    red_acc[0][w][4 * lg + r][lm] = o0A[r];
    red_acc[0][w][16 + 4 * lg + r][lm] = o0B[r];
    red_acc[1][w][4 * lg + r][lm] = o1A[r];
    red_acc[1][w][16 + 4 * lg + r][lm] = o1B[r];
  }
  __syncthreads();
  #pragma unroll
  for (int rep = 0; rep < 2; ++rep) {
    int idx = tid + rep * 512;   // hh*512 + cl*16 + mm
    int hh = idx >> 9, cl = (idx >> 4) & 31, mm = idx & 15;
    float lsum = 0.f, osum = 0.f;
    #pragma unroll
    for (int ww = 0; ww < 8; ++ww) {
      lsum += red_l[hh][ww][mm];
      osum += red_acc[hh][ww][cl][mm];
    }
    att[(size_t)((h0 + hh) * 32 + cl) * HW + m0 + mm] = osum / lsum;
  }
}

extern "C" void kernel_launch(void* const* d_in, const int* in_sizes, int n_in,
                              void* d_out, int out_size, void* d_ws, size_t ws_size,
                              hipStream_t stream) {
  const float* x    = (const float*)d_in[0];
  const float* wq   = (const float*)d_in[1];
  const float* bq   = (const float*)d_in[2];
  const float* wk   = (const float*)d_in[3];
  const float* bk   = (const float*)d_in[4];
  const float* wv   = (const float*)d_in[5];
  const float* bv   = (const float*)d_in[6];
  const float* wdw  = (const float*)d_in[7];
  const float* bdw  = (const float*)d_in[8];
  const float* lng  = (const float*)d_in[9];
  const float* lnb  = (const float*)d_in[10];
  const float* wpw  = (const float*)d_in[11];
  const float* rpe  = (const float*)d_in[12];
  const float* wout = (const float*)d_in[13];
  const float* bout = (const float*)d_in[14];
  float* out = (float*)d_out;

  float* ws = (float*)d_ws;
  float* q_f32 = ws;                                        // 4MB (reused as xs)
  float* o_f32 = ws + (1 << 20);                            // 4MB (reused as att)
  unsigned short* qt  = (unsigned short*)(ws + (2 << 20));  // 2MB
  unsigned short* ktp = (unsigned short*)(ws + ((2 << 20) + (1 << 19)));  // 2MB
  unsigned short* vbp = (unsigned short*)(ws + (3 << 20));  // 2MB
  float* pos  = ws + ((3 << 20) + (1 << 19));               // 128KB
  float* cxy  = pos + 32768;                                // 128KB
  unsigned int* tab4 = (unsigned int*)(cxy + 32768);        // 1.06MB

  gemm256<<<512, 256, 0, stream>>>(wq, bq, x, q_f32, qt, SCALE * LOG2E);
  build_rpe4_kernel<<<521, 256, 0, stream>>>(rpe, tab4);
  dwconv_kernel<<<512, 256, 0, stream>>>(q_f32, wdw, bdw, o_f32);
  ln_offset_kernel<<<4096, 256, 0, stream>>>(o_f32, lng, lnb, wpw, pos, cxy);
  sample_kernel<<<1024, 256, 0, stream>>>(x, pos, q_f32);   // q_f32 := xs
  gemm_kv<<<512, 256, 0, stream>>>(wk, bk, wv, bv, q_f32, ktp, vbp);
  attn_kernel<<<1024, 512, 0, stream>>>(qt, ktp, vbp, cxy, tab4, o_f32);  // o_f32 := att
  gemm256<<<512, 256, 0, stream>>>(wout, bout, o_f32, out, nullptr, 1.0f);
}

// Round 22
// 266.491 us; speedup vs baseline: 1.1269x; 1.0313x over previous
//
#include <hip/hip_runtime.h>
#include <hip/hip_bf16.h>
#include <math.h>

#define HW 4096
#define SCALE 0.17677669529663687f
#define LOG2E 1.4426950408889634f

typedef __attribute__((ext_vector_type(8))) short short8;
typedef __attribute__((ext_vector_type(4))) float f32x4;
typedef __attribute__((ext_vector_type(4))) unsigned int u32x4;
typedef __attribute__((ext_vector_type(2))) unsigned int u32x2;
typedef __attribute__((ext_vector_type(2), aligned(8))) unsigned int u32x2a;

static __device__ __forceinline__ unsigned short bf16b(float f) {
  __hip_bfloat16 h = __float2bfloat16(f);
  return *reinterpret_cast<unsigned short*>(&h);
}

// ---- GEMM: Y[256][4096] = W @ X + b. 1 px/thread, o-tile 8, grid 512 (2 blocks/CU).
__global__ __launch_bounds__(256) void gemm256(const float* __restrict__ W,
                                               const float* __restrict__ bias,
                                               const float* __restrict__ X,
                                               float* __restrict__ Yf,
                                               unsigned short* __restrict__ Yt,
                                               float sc) {
  int tid = threadIdx.x;
  int o0 = (blockIdx.x >> 4) * 8;          // 32 o-groups
  int p = (blockIdx.x & 15) * 256 + tid;   // 16 p-tiles of 256
  const float* Wb = W + o0 * 256;
  float acc[8];
  #pragma unroll
  for (int i = 0; i < 8; ++i) acc[i] = 0.f;
  #pragma unroll 8
  for (int c = 0; c < 256; ++c) {
    float xv = X[c * HW + p];
    #pragma unroll
    for (int i = 0; i < 8; ++i) acc[i] += Wb[i * 256 + c] * xv;
  }
  float r[8];
  #pragma unroll
  for (int i = 0; i < 8; ++i) r[i] = acc[i] + bias[o0 + i];
  if (Yf) {
    #pragma unroll
    for (int i = 0; i < 8; ++i) Yf[(size_t)(o0 + i) * HW + p] = r[i];
  }
  if (Yt) {
    int h = o0 >> 5, c0 = o0 & 31;
    u32x4 pk;
    #pragma unroll
    for (int j = 0; j < 4; ++j)
      pk[j] = (unsigned int)bf16b(r[2 * j] * sc) | ((unsigned int)bf16b(r[2 * j + 1] * sc) << 16);
    *(u32x4*)(Yt + ((size_t)(h * HW + p) * 32 + c0)) = pk;
  }
}

// ---- fused K+V projection, 1 px/thread, grid 512 ----
__global__ __launch_bounds__(256) void gemm_kv(const float* __restrict__ Wk,
                                               const float* __restrict__ bk,
                                               const float* __restrict__ Wv,
                                               const float* __restrict__ bv,
                                               const float* __restrict__ X,
                                               unsigned short* __restrict__ Yt,
                                               unsigned short* __restrict__ Yv) {
  int tid = threadIdx.x;
  int o0 = (blockIdx.x >> 4) * 8;
  int p = (blockIdx.x & 15) * 256 + tid;
  const float* Wkb = Wk + o0 * 256;
  const float* Wvb = Wv + o0 * 256;
  float ka[8], va[8];
  #pragma unroll
  for (int i = 0; i < 8; ++i) { ka[i] = 0.f; va[i] = 0.f; }
  #pragma unroll 4
  for (int c = 0; c < 256; ++c) {
    float xv = X[c * HW + p];
    #pragma unroll
    for (int i = 0; i < 8; ++i) {
      ka[i] += Wkb[i * 256 + c] * xv;
      va[i] += Wvb[i * 256 + c] * xv;
    }
  }
  {
    int h = o0 >> 5, c0 = o0 & 31;
    u32x4 pk;
    #pragma unroll
    for (int j = 0; j < 4; ++j) {
      float k0 = ka[2 * j] + bk[o0 + 2 * j];
      float k1 = ka[2 * j + 1] + bk[o0 + 2 * j + 1];
      pk[j] = (unsigned int)bf16b(k0) | ((unsigned int)bf16b(k1) << 16);
    }
    *(u32x4*)(Yt + ((size_t)(h * HW + p) * 32 + c0)) = pk;
  }
  #pragma unroll
  for (int i = 0; i < 8; ++i)
    Yv[(size_t)(o0 + i) * HW + p] = bf16b(va[i] + bv[o0 + i]);
}

// ---- depthwise 9x9 conv: 8 y-outputs per thread, 16-row sliding window ----
__global__ __launch_bounds__(256) void dwconv_kernel(const float* __restrict__ q,
                                                     const float* __restrict__ wdw,
                                                     const float* __restrict__ bdw,
                                                     float* __restrict__ o) {
  int x = threadIdx.x & 63;
  int w = threadIdx.x >> 6;
  int bid = blockIdx.x;               // g*128 + c*2 + half
  int half = bid & 1; int c = (bid >> 1) & 63; int g = bid >> 7;
  int y0 = half * 32 + w * 8;
  const float* qc = q + (g * 64 + c) * HW;
  const float* wc = wdw + c * 81;
  float b = bdw[c];
  float acc[8];
  #pragma unroll
  for (int i = 0; i < 8; ++i) acc[i] = b;
  #pragma unroll
  for (int r = 0; r < 16; ++r) {
    int yy = y0 - 4 + r;
    bool rowok = (unsigned)yy <= 63u;
    int yc = min(max(yy, 0), 63);
    float v[9];
    #pragma unroll
    for (int kx = 0; kx < 9; ++kx) {
      int xx = x + kx - 4;
      bool ok = rowok && ((unsigned)xx <= 63u);
      int xc = min(max(xx, 0), 63);
      float lv = qc[yc * 64 + xc];
      v[kx] = ok ? lv : 0.f;
    }
    #pragma unroll
    for (int oy = 0; oy < 8; ++oy) {
      int ky = r - oy;
      if (ky < 0 || ky > 8) continue;
      #pragma unroll
      for (int kx = 0; kx < 9; ++kx)
        acc[oy] += wc[ky * 9 + kx] * v[kx];
    }
  }
  #pragma unroll
  for (int oy = 0; oy < 8; ++oy)
    o[(g * 64 + c) * HW + (y0 + oy) * 64 + x] = acc[oy];
}

// ---- LN + GELU + pointwise + tanh -> pos/cxy (shuffle version, grid 4096) ----
__global__ __launch_bounds__(256) void ln_offset_kernel(const float* __restrict__ o,
                                                        const float* __restrict__ ln_g,
                                                        const float* __restrict__ ln_b,
                                                        const float* __restrict__ wpw,
                                                        float* __restrict__ pos,
                                                        float* __restrict__ cxy) {
  int wave = threadIdx.x >> 6;
  int c = threadIdx.x & 63;
  int bid = blockIdx.x;
  int xc = bid & 15; int y = (bid >> 4) & 63; int g = bid >> 10;
  int x = xc * 4 + wave;
  int p = y * 64 + x;
  float v = o[(g * 64 + c) * HW + p];
  float s = v, s2 = v * v;
  #pragma unroll
  for (int m = 32; m; m >>= 1) { s += __shfl_xor(s, m); s2 += __shfl_xor(s2, m); }
  float mu = s * (1.f / 64.f);
  float var = s2 * (1.f / 64.f) - mu * mu;
  float nv = (v - mu) * rsqrtf(var + 1e-5f) * ln_g[c] + ln_b[c];
  nv = 0.5f * nv * (1.f + erff(nv * 0.70710678118654752f));
  float t0 = wpw[c] * nv, t1 = wpw[64 + c] * nv;
  #pragma unroll
  for (int m = 32; m; m >>= 1) { t0 += __shfl_xor(t0, m); t1 += __shfl_xor(t1, m); }
  if (c == 0) {
    float offy = tanhf(t0) * (2.0f / 64.0f);
    float offx = tanhf(t1) * (2.0f / 64.0f);
    float py = offy + (y + 0.5f) * (2.f / 64.f) - 1.f;
    float px = offx + (x + 0.5f) * (2.f / 64.f) - 1.f;
    pos[(g * HW + p) * 2 + 0] = py;
    pos[(g * HW + p) * 2 + 1] = px;
    cxy[(g * HW + p) * 2 + 0] = 64.0f - 31.5f * px;
    cxy[(g * HW + p) * 2 + 1] = 64.0f - 31.5f * py;
  }
}

// ---- bilinear sample of x at pos -> xs[256][4096]; 4 channels/thread, grid 1024 ----
__global__ __launch_bounds__(256) void sample_kernel(const float* __restrict__ x,
                                                     const float* __restrict__ pos,
                                                     float* __restrict__ xs) {
  int bid = blockIdx.x;  // g*256 + nt*16 + cc
  int cc = bid & 15; int nt = (bid >> 4) & 15; int g = bid >> 8;
  int n = nt * 256 + threadIdx.x;
  float py = pos[(g * HW + n) * 2 + 0];
  float px = pos[(g * HW + n) * 2 + 1];
  float gx = (px + 1.f) * 31.5f;
  float gy = (py + 1.f) * 31.5f;
  float xf = floorf(gx), yf = floorf(gy);
  int xi = (int)xf, yi = (int)yf;
  float fx = gx - xf, fy = gy - yf;
  int x0c = min(max(xi, 0), 63), x1c = min(max(xi + 1, 0), 63);
  int y0c = min(max(yi, 0), 63), y1c = min(max(yi + 1, 0), 63);
  float wx0 = ((unsigned)xi <= 63u) ? (1.f - fx) : 0.f;
  float wx1 = ((unsigned)(xi + 1) <= 63u) ? fx : 0.f;
  float wy0 = ((unsigned)yi <= 63u) ? (1.f - fy) : 0.f;
  float wy1 = ((unsigned)(yi + 1) <= 63u) ? fy : 0.f;
  #pragma unroll
  for (int ci = 0; ci < 4; ++ci) {
    int c = cc * 4 + ci;
    const float* xp = x + (g * 64 + c) * HW;
    float vsum = wy0 * (wx0 * xp[y0c * 64 + x0c] + wx1 * xp[y0c * 64 + x1c]) +
                 wy1 * (wx0 * xp[y1c * 64 + x0c] + wx1 * xp[y1c * 64 + x1c]);
    xs[(g * 64 + c) * HW + n] = vsum;
  }
}

// ---- build 4-corner bf16-packed, zero-padded, log2e-scaled RPE tables ----
__global__ __launch_bounds__(256) void build_rpe4_kernel(const float* __restrict__ rpe,
                                                         unsigned int* __restrict__ tab4) {
  int idx = blockIdx.x * 256 + threadIdx.x;
  if (idx >= 8 * 16641) return;
  int h = idx / 16641; int r = idx - h * 16641;
  int y = r / 129, x = r - y * 129;
  const float* tb = rpe + h * 16129;
  auto pad = [&](int yy, int xx) -> float {
    if (yy < 1 || yy > 127 || xx < 1 || xx > 127) return 0.f;
    return tb[(yy - 1) * 127 + (xx - 1)] * LOG2E;
  };
  unsigned int w0 = (unsigned int)bf16b(pad(y, x)) | ((unsigned int)bf16b(pad(y + 1, x)) << 16);
  unsigned int w1 = (unsigned int)bf16b(pad(y, x + 1)) | ((unsigned int)bf16b(pad(y + 1, x + 1)) << 16);
  u32x2 v = {w0, w1};
  *(u32x2*)(tab4 + (size_t)idx * 2) = v;
}

// ---- fused attention: 2 heads/block, shared addr math, cxy loaded in-iteration ----
// Loop-carried state: K frags (4 short8), bias0/bias1 (16 f). cxy/gathers resolve
// within each iteration body (issued early, consumed at end).
__global__ __launch_bounds__(256, 3) void attn_kernel(const unsigned short* __restrict__ qt,
                                                      const unsigned short* __restrict__ kt,
                                                      const unsigned short* __restrict__ vbuf,
                                                      const float* __restrict__ cxy,
                                                      const unsigned int* __restrict__ tab4,
                                                      float* __restrict__ att) {
  __shared__ __align__(16) unsigned char smem[16896];
  auto P_pack = reinterpret_cast<unsigned int(*)[4][16][20]>(smem);        // [2][4][16][20] = 10240B
  auto red_l = reinterpret_cast<float(*)[4][16]>(smem);                    // [2][4][16] = 512B
  auto red_acc = reinterpret_cast<float(*)[4][32][16]>(smem + 512);        // [2][4][32][16] = 16384B

  int tid = threadIdx.x;
  int w = tid >> 6;
  int l = tid & 63;
  int lm = l & 15;   // column: query m
  int lg = l >> 4;   // lane group
  int g = blockIdx.x >> 8;
  int mt = blockIdx.x & 255;
  int m0 = mt * 16;
  int m = m0 + lm;
  int xm = m & 63, ym = m >> 6;
  float ex = (xm + 0.5f) * (63.0f / 64.0f) - 31.5f;
  float ey = (ym + 0.5f) * (63.0f / 64.0f) - 31.5f;
  int h0 = g * 2;
  const char* tb0 = (const char*)tab4 + (size_t)h0 * 133128;
  const char* tb1 = tb0 + 133128;
  const float* cbase = cxy + (size_t)g * HW * 2;
  const unsigned short* v0row0 = vbuf + (size_t)(h0 * 32 + lm) * HW;
  const unsigned short* v0row1 = vbuf + (size_t)(h0 * 32 + 16 + lm) * HW;
  const unsigned short* v1row0 = vbuf + (size_t)((h0 + 1) * 32 + lm) * HW;
  const unsigned short* v1row1 = vbuf + (size_t)((h0 + 1) * 32 + 16 + lm) * HW;

  short8 qf0 = *(const short8*)(qt + ((size_t)(h0 * HW + m) * 32 + 8 * lg));
  short8 qf1 = *(const short8*)(qt + ((size_t)((h0 + 1) * HW + m) * 32 + 8 * lg));

  f32x4 o0A = {0.f, 0.f, 0.f, 0.f}, o0B = {0.f, 0.f, 0.f, 0.f};
  f32x4 o1A = {0.f, 0.f, 0.f, 0.f}, o1B = {0.f, 0.f, 0.f, 0.f};
  float l0 = 0.f, l1 = 0.f;

  // ---------------- prologue: bias for it=0, K for it=0 ----------------
  float bias0[8], bias1[8];
  short8 k0a, k0b, k1a, k1b;

  {
    int n0 = w * 32;
    k0a = *(const short8*)(kt + ((size_t)(h0 * HW + n0 + lm) * 32 + 8 * lg));
    k0b = *(const short8*)(kt + ((size_t)(h0 * HW + n0 + 16 + lm) * 32 + 8 * lg));
    k1a = *(const short8*)(kt + ((size_t)((h0 + 1) * HW + n0 + lm) * 32 + 8 * lg));
    k1b = *(const short8*)(kt + ((size_t)((h0 + 1) * HW + n0 + 16 + lm) * 32 + 8 * lg));
    u32x2a t0[8], t1[8];
    float fxs[8], fys[8];
    #pragma unroll
    for (int i = 0; i < 8; ++i) {
      int nl = 16 * (i >> 2) + 4 * lg + (i & 3);
      float2 cc = *(const float2*)(cbase + (size_t)(n0 + nl) * 2);
      float gx = ex + cc.x, gy = ey + cc.y;
      float xf = floorf(gx), yf = floorf(gy);
      fxs[i] = gx - xf; fys[i] = gy - yf;
      unsigned off = (unsigned)((int)yf * 1032 + ((int)xf << 3));
      t0[i] = *(const u32x2a*)(tb0 + off);
      t1[i] = *(const u32x2a*)(tb1 + off);
    }
    #pragma unroll
    for (int i = 0; i < 8; ++i) {
      float a00 = __uint_as_float(t0[i][0] << 16);
      float a10 = __uint_as_float(t0[i][0] & 0xffff0000u);
      float a01 = __uint_as_float(t0[i][1] << 16);
      float a11 = __uint_as_float(t0[i][1] & 0xffff0000u);
      float ly0 = a00 + fys[i] * (a10 - a00);
      float ly1 = a01 + fys[i] * (a11 - a01);
      bias0[i] = ly0 + fxs[i] * (ly1 - ly0);
      float b00 = __uint_as_float(t1[i][0] << 16);
      float b10 = __uint_as_float(t1[i][0] & 0xffff0000u);
      float b01 = __uint_as_float(t1[i][1] << 16);
      float b11 = __uint_as_float(t1[i][1] & 0xffff0000u);
      float my0 = b00 + fys[i] * (b10 - b00);
      float my1 = b01 + fys[i] * (b11 - b01);
      bias1[i] = my0 + fxs[i] * (my1 - my0);
    }
  }

  // ---------------- main loop ----------------
  for (int it = 0; it < 32; ++it) {
    int n0 = it * 128 + w * 32;
    int n0n = ((it + 1) & 31) * 128 + w * 32;

    // cxy for it+1 (L2-linear; consumed by gathers mid-iteration)
    float2 ccn[8];
    #pragma unroll
    for (int i = 0; i < 8; ++i) {
      int nl = 16 * (i >> 2) + 4 * lg + (i & 3);
      ccn[i] = *(const float2*)(cbase + (size_t)(n0n + nl) * 2);
    }
    // V for CURRENT iteration (consumed after softmax)
    short8 v0a = *(const short8*)(v0row0 + n0 + 8 * lg);
    short8 v0b = *(const short8*)(v0row1 + n0 + 8 * lg);
    short8 v1a = *(const short8*)(v1row0 + n0 + 8 * lg);
    short8 v1b = *(const short8*)(v1row1 + n0 + 8 * lg);

    f32x4 z = {0.f, 0.f, 0.f, 0.f};
    f32x4 s0a = __builtin_amdgcn_mfma_f32_16x16x32_bf16(k0a, qf0, z, 0, 0, 0);
    f32x4 s0b = __builtin_amdgcn_mfma_f32_16x16x32_bf16(k0b, qf0, z, 0, 0, 0);
    f32x4 s1a = __builtin_amdgcn_mfma_f32_16x16x32_bf16(k1a, qf1, z, 0, 0, 0);
    f32x4 s1b = __builtin_amdgcn_mfma_f32_16x16x32_bf16(k1b, qf1, z, 0, 0, 0);

    // prefetch K for it+1
    short8 k0an = *(const short8*)(kt + ((size_t)(h0 * HW + n0n + lm) * 32 + 8 * lg));
    short8 k0bn = *(const short8*)(kt + ((size_t)(h0 * HW + n0n + 16 + lm) * 32 + 8 * lg));
    short8 k1an = *(const short8*)(kt + ((size_t)((h0 + 1) * HW + n0n + lm) * 32 + 8 * lg));
    short8 k1bn = *(const short8*)(kt + ((size_t)((h0 + 1) * HW + n0n + 16 + lm) * 32 + 8 * lg));

    // table gathers for it+1 (addresses from just-loaded ccn; shared, two tables)
    u32x2a t0[8], t1[8];
    float fxs[8], fys[8];
    #pragma unroll
    for (int i = 0; i < 8; ++i) {
      float gx = ex + ccn[i].x, gy = ey + ccn[i].y;
      float xf = floorf(gx), yf = floorf(gy);
      fxs[i] = gx - xf; fys[i] = gy - yf;
      unsigned off = (unsigned)((int)yf * 1032 + ((int)xf << 3));
      t0[i] = *(const u32x2a*)(tb0 + off);
      t1[i] = *(const u32x2a*)(tb1 + off);
    }

    // softmax for it (both heads)
    float p0[8], p1[8];
    #pragma unroll
    for (int i = 0; i < 8; ++i) {
      float q0 = (i < 4) ? s0a[i & 3] : s0b[i & 3];
      float q1 = (i < 4) ? s1a[i & 3] : s1b[i & 3];
      p0[i] = __builtin_amdgcn_exp2f(q0 + bias0[i]);
      p1[i] = __builtin_amdgcn_exp2f(q1 + bias1[i]);
    }
    l0 += ((p0[0] + p0[1]) + (p0[2] + p0[3])) + ((p0[4] + p0[5]) + (p0[6] + p0[7]));
    l1 += ((p1[0] + p1[1]) + (p1[2] + p1[3])) + ((p1[4] + p1[5]) + (p1[6] + p1[7]));
    {
      unsigned int w0 = (unsigned int)bf16b(p0[0]) | ((unsigned int)bf16b(p0[1]) << 16);
      unsigned int w1 = (unsigned int)bf16b(p0[2]) | ((unsigned int)bf16b(p0[3]) << 16);
      unsigned int w2 = (unsigned int)bf16b(p0[4]) | ((unsigned int)bf16b(p0[5]) << 16);
      unsigned int w3 = (unsigned int)bf16b(p0[6]) | ((unsigned int)bf16b(p0[7]) << 16);
      u32x2 wa = {w0, w1}, wb = {w2, w3};
      *(u32x2*)&P_pack[0][w][lm][2 * lg] = wa;
      *(u32x2*)&P_pack[0][w][lm][8 + 2 * lg] = wb;
    }
    {
      unsigned int w0 = (unsigned int)bf16b(p1[0]) | ((unsigned int)bf16b(p1[1]) << 16);
      unsigned int w1 = (unsigned int)bf16b(p1[2]) | ((unsigned int)bf16b(p1[3]) << 16);
      unsigned int w2 = (unsigned int)bf16b(p1[4]) | ((unsigned int)bf16b(p1[5]) << 16);
      unsigned int w3 = (unsigned int)bf16b(p1[6]) | ((unsigned int)bf16b(p1[7]) << 16);
      u32x2 wa = {w0, w1}, wb = {w2, w3};
      *(u32x2*)&P_pack[1][w][lm][2 * lg] = wa;
      *(u32x2*)&P_pack[1][w][lm][8 + 2 * lg] = wb;
    }
    {
      u32x4 pw0 = *(u32x4*)&P_pack[0][w][lm][4 * lg];
      union { u32x4 u; short8 s; } c0; c0.u = pw0;
      o0A = __builtin_amdgcn_mfma_f32_16x16x32_bf16(v0a, c0.s, o0A, 0, 0, 0);
      o0B = __builtin_amdgcn_mfma_f32_16x16x32_bf16(v0b, c0.s, o0B, 0, 0, 0);
      u32x4 pw1 = *(u32x4*)&P_pack[1][w][lm][4 * lg];
      union { u32x4 u; short8 s; } c1; c1.u = pw1;
      o1A = __builtin_amdgcn_mfma_f32_16x16x32_bf16(v1a, c1.s, o1A, 0, 0, 0);
      o1B = __builtin_amdgcn_mfma_f32_16x16x32_bf16(v1b, c1.s, o1B, 0, 0, 0);
    }

    // finish bias for it+1 (both heads)
    #pragma unroll
    for (int i = 0; i < 8; ++i) {
      float a00 = __uint_as_float(t0[i][0] << 16);
      float a10 = __uint_as_float(t0[i][0] & 0xffff0000u);
      float a01 = __uint_as_float(t0[i][1] << 16);
      float a11 = __uint_as_float(t0[i][1] & 0xffff0000u);
      float ly0 = a00 + fys[i] * (a10 - a00);
      float ly1 = a01 + fys[i] * (a11 - a01);
      bias0[i] = ly0 + fxs[i] * (ly1 - ly0);
      float b00 = __uint_as_float(t1[i][0] << 16);
      float b10 = __uint_as_float(t1[i][0] & 0xffff0000u);
      float b01 = __uint_as_float(t1[i][1] << 16);
      float b11 = __uint_as_float(t1[i][1] & 0xffff0000u);
      float my0 = b00 + fys[i] * (b10 - b00);
      float my1 = b01 + fys[i] * (b11 - b01);
      bias1[i] = my0 + fxs[i] * (my1 - my0);
    }
    k0a = k0an; k0b = k0bn;
    k1a = k1an; k1b = k1bn;
  }

  // ---------------- epilogue: cross-wave merge (LDS reused; barrier-separated) ----------------
  __syncthreads();   // all waves done with P_pack before red_* overwrite it
  l0 += __shfl_xor(l0, 16); l0 += __shfl_xor(l0, 32);
  l1 += __shfl_xor(l1, 16); l1 += __shfl_xor(l1, 32);
  if (lg == 0) { red_l[0][w][lm] = l0; red_l[1][w][lm] = l1; }
  #pragma unroll
  for (int r = 0; r < 4; ++r) {
    red_acc[0][w][4 * lg + r][lm] = o0A[r];
    red_acc[0][w][16 + 4 * lg + r][lm] = o0B[r];
    red_acc[1][w][4 * lg + r][lm] = o1A[r];
    red_acc[1][w][16 + 4 * lg + r][lm] = o1B[r];
  }
  __syncthreads();
  #pragma unroll
  for (int rep = 0; rep < 8; ++rep) {
    int idx = tid + rep * 256;   // hh*1024 + cl*16 + mm
    int hh = idx >> 10, cl = (idx >> 4) & 31, mm = idx & 15;
    float lsum = 0.f, osum = 0.f;
    #pragma unroll
    for (int ww = 0; ww < 4; ++ww) {
      lsum += red_l[hh][ww][mm];
      osum += red_acc[hh][ww][cl][mm];
    }
    att[(size_t)((h0 + hh) * 32 + cl) * HW + m0 + mm] = osum / lsum;
  }
}

extern "C" void kernel_launch(void* const* d_in, const int* in_sizes, int n_in,
                              void* d_out, int out_size, void* d_ws, size_t ws_size,
                              hipStream_t stream) {
  const float* x    = (const float*)d_in[0];
  const float* wq   = (const float*)d_in[1];
  const float* bq   = (const float*)d_in[2];
  const float* wk   = (const float*)d_in[3];
  const float* bk   = (const float*)d_in[4];
  const float* wv   = (const float*)d_in[5];
  const float* bv   = (const float*)d_in[6];
  const float* wdw  = (const float*)d_in[7];
  const float* bdw  = (const float*)d_in[8];
  const float* lng  = (const float*)d_in[9];
  const float* lnb  = (const float*)d_in[10];
  const float* wpw  = (const float*)d_in[11];
  const float* rpe  = (const float*)d_in[12];
  const float* wout = (const float*)d_in[13];
  const float* bout = (const float*)d_in[14];
  float* out = (float*)d_out;

  float* ws = (float*)d_ws;
  float* q_f32 = ws;                                        // 4MB (reused as xs)
  float* o_f32 = ws + (1 << 20);                            // 4MB (reused as att)
  unsigned short* qt  = (unsigned short*)(ws + (2 << 20));  // 2MB
  unsigned short* ktp = (unsigned short*)(ws + ((2 << 20) + (1 << 19)));  // 2MB
  unsigned short* vbp = (unsigned short*)(ws + (3 << 20));  // 2MB
  float* pos  = ws + ((3 << 20) + (1 << 19));               // 128KB
  float* cxy  = pos + 32768;                                // 128KB
  unsigned int* tab4 = (unsigned int*)(cxy + 32768);        // 1.06MB

  gemm256<<<512, 256, 0, stream>>>(wq, bq, x, q_f32, qt, SCALE * LOG2E);
  build_rpe4_kernel<<<521, 256, 0, stream>>>(rpe, tab4);
  dwconv_kernel<<<512, 256, 0, stream>>>(q_f32, wdw, bdw, o_f32);
  ln_offset_kernel<<<4096, 256, 0, stream>>>(o_f32, lng, lnb, wpw, pos, cxy);
  sample_kernel<<<1024, 256, 0, stream>>>(x, pos, q_f32);   // q_f32 := xs
  gemm_kv<<<512, 256, 0, stream>>>(wk, bk, wv, bv, q_f32, ktp, vbp);
  attn_kernel<<<1024, 256, 0, stream>>>(qt, ktp, vbp, cxy, tab4, o_f32);  // o_f32 := att
  gemm256<<<512, 256, 0, stream>>>(wout, bout, o_f32, out, nullptr, 1.0f);
}